// Round 13
// baseline (1237.371 us; speedup 1.0000x reference)
//
#include <hip/hip_runtime.h>

// ---------------------------------------------------------------------------
// Transformer: rbb resnet (2 blocks) -> 4 attention layers -> rba resnet.
// Round 13: gemm_qkv + geometry reverted to R9. Attention: LDS staging
// DELETED (m169 pattern) — kf/vb fragments read directly from global;
// K+VT per bh (512KB) x 8 bh/XCD = 4MB L2-resident, per-tile 16KB
// L1-resident. No barriers in the K-loop; vb loads issued before softmax
// so L2 latency hides under the VALU phase.
// ---------------------------------------------------------------------------

typedef __bf16 bf16x8 __attribute__((ext_vector_type(8)));
typedef __bf16 bf16x4 __attribute__((ext_vector_type(4)));
typedef float  f32x4  __attribute__((ext_vector_type(4)));
typedef float  f32x16 __attribute__((ext_vector_type(16)));

#define SCQ 0.18033688011112042f   // log2(e)/8, folded into Q projection

__device__ __forceinline__ void gl_lds16(const void* g, void* l) {
  __builtin_amdgcn_global_load_lds(
      (const __attribute__((address_space(1))) void*)g,
      (__attribute__((address_space(3))) void*)l, 16, 0, 0);
}

// ---------------------------------------------------------------------------
// Weight convert+transpose: W f32 [1024][1024] -> WT bf16 [n][k].
// Order: 0-3 rbb, 4..15 per-layer QKV (Wq|Wk|Wv contiguous), 16-19 Wo,
// 20-23 rba.
// ---------------------------------------------------------------------------
__global__ __launch_bounds__(256) void wt_conv(
    const float* __restrict__ rbbW, const float* __restrict__ Wq,
    const float* __restrict__ Wk,   const float* __restrict__ Wv,
    const float* __restrict__ Wo,   const float* __restrict__ rbaW,
    __bf16* __restrict__ out)
{
  int bid = blockIdx.x;
  int m = bid >> 10;
  int tile = bid & 1023;
  int tr = tile >> 5, tc = tile & 31;
  const float* src;
  if (m < 4)       src = rbbW + (size_t)m * 1048576;
  else if (m < 16) {
    int l = (m - 4) / 3, r = (m - 4) % 3;
    const float* w3 = (r == 0) ? Wq : (r == 1) ? Wk : Wv;
    src = w3 + (size_t)l * 1048576;
  }
  else if (m < 20) src = Wo   + (size_t)(m - 16) * 1048576;
  else             src = rbaW + (size_t)(m - 20) * 1048576;
  __bf16* dst = out + (size_t)m * 1048576;

  __shared__ float tileS[32][33];
  int tx = threadIdx.x & 31, ty = threadIdx.x >> 5;
#pragma unroll
  for (int i = 0; i < 32; i += 8)
    tileS[ty + i][tx] = src[(size_t)(tr * 32 + ty + i) * 1024 + tc * 32 + tx];
  __syncthreads();
#pragma unroll
  for (int i = 0; i < 32; i += 8)
    dst[(size_t)(tc * 32 + ty + i) * 1024 + tr * 32 + tx] = (__bf16)tileS[tx][ty + i];
}

// ---------------------------------------------------------------------------
// LayerNorm + ReLU, [row][1024] -> bf16 [row][1024]. INBF: input dtype.
// ---------------------------------------------------------------------------
template <int INBF>
__global__ __launch_bounds__(256) void ln_relu(
    const void* __restrict__ inv, const float* __restrict__ g,
    const float* __restrict__ bta, __bf16* __restrict__ out)
{
  int row = blockIdx.x;
  int t = threadIdx.x;
  float4 v;
  if constexpr (INBF) {
    bf16x4 b4 = ((const bf16x4*)((const __bf16*)inv + (size_t)row * 1024))[t];
    v = make_float4((float)b4[0], (float)b4[1], (float)b4[2], (float)b4[3]);
  } else {
    v = ((const float4*)((const float*)inv + (size_t)row * 1024))[t];
  }
  float s  = v.x + v.y + v.z + v.w;
  float s2 = v.x * v.x + v.y * v.y + v.z * v.z + v.w * v.w;
#pragma unroll
  for (int o = 32; o > 0; o >>= 1) {
    s  += __shfl_xor(s, o);
    s2 += __shfl_xor(s2, o);
  }
  __shared__ float rs[4], rs2[4];
  int w = t >> 6, lane = t & 63;
  if (lane == 0) { rs[w] = s; rs2[w] = s2; }
  __syncthreads();
  s  = rs[0] + rs[1] + rs[2] + rs[3];
  s2 = rs2[0] + rs2[1] + rs2[2] + rs2[3];
  float mu  = s * (1.0f / 1024.0f);
  float var = s2 * (1.0f / 1024.0f) - mu * mu;
  float ri  = rsqrtf(var + 1e-5f);
  float4 gv = ((const float4*)g)[t];
  float4 bv = ((const float4*)bta)[t];
  float y0 = fmaxf(0.f, (v.x - mu) * ri * gv.x + bv.x);
  float y1 = fmaxf(0.f, (v.y - mu) * ri * gv.y + bv.y);
  float y2 = fmaxf(0.f, (v.z - mu) * ri * gv.z + bv.z);
  float y3 = fmaxf(0.f, (v.w - mu) * ri * gv.w + bv.w);
  bf16x4 o4 = { (__bf16)y0, (__bf16)y1, (__bf16)y2, (__bf16)y3 };
  *(bf16x4*)(out + (size_t)row * 1024 + t * 4) = o4;
}

// ---------------------------------------------------------------------------
// GEMM K-loop BK=64: 128x128 tile, 2-buffer, counted vmcnt(8), raw barriers.
// LDS [row][64] with 16B-group XOR swizzle g^(row&7), source-pre-swizzled.
// ---------------------------------------------------------------------------
#define STAGE8(k0, nb)                                                         \
  {                                                                            \
    const __bf16* Ak = Ag + (k0);                                              \
    const __bf16* Bk = Bg + (k0);                                              \
    char* Ad = (char*)As + (nb) * 16384 + w * 1024;                            \
    char* Bd = (char*)Bs + (nb) * 16384 + w * 1024;                            \
    gl_lds16(Ak,         Ad);                                                  \
    gl_lds16(Ak + 32768, Ad + 4096);                                           \
    gl_lds16(Ak + 65536, Ad + 8192);                                           \
    gl_lds16(Ak + 98304, Ad + 12288);                                          \
    gl_lds16(Bk,         Bd);                                                  \
    gl_lds16(Bk + 32768, Bd + 4096);                                           \
    gl_lds16(Bk + 65536, Bd + 8192);                                           \
    gl_lds16(Bk + 98304, Bd + 12288);                                          \
  }

#define GEMM_KLOOP64(acc)                                                      \
  STAGE8(0, 0)                                                                 \
  for (int t = 0; t < 16; ++t) {                                               \
    __builtin_amdgcn_s_barrier();                                              \
    if (t < 15) {                                                              \
      STAGE8((t + 1) * 64, (t + 1) & 1)                                        \
      asm volatile("s_waitcnt vmcnt(8)" ::: "memory");                         \
    } else {                                                                   \
      asm volatile("s_waitcnt vmcnt(0)" ::: "memory");                         \
    }                                                                          \
    __builtin_amdgcn_s_barrier();                                              \
    const __bf16* Asb = As + (t & 1) * 8192;                                   \
    const __bf16* Bsb = Bs + (t & 1) * 8192;                                   \
    _Pragma("unroll")                                                          \
    for (int kk = 0; kk < 2; kk++) {                                           \
      bf16x8 a[4], b[4];                                                       \
      _Pragma("unroll")                                                        \
      for (int mi = 0; mi < 4; mi++)                                           \
        a[mi] = *(const bf16x8*)&Asb[(wr * 64 + mi * 16 + fr) * 64 +           \
                                     (((kk * 4 + fq) ^ (fr & 7)) * 8)];        \
      _Pragma("unroll")                                                        \
      for (int ni = 0; ni < 4; ni++)                                           \
        b[ni] = *(const bf16x8*)&Bsb[(wc * 64 + ni * 16 + fr) * 64 +           \
                                     (((kk * 4 + fq) ^ (fr & 7)) * 8)];        \
      _Pragma("unroll")                                                        \
      for (int mi = 0; mi < 4; mi++)                                           \
        _Pragma("unroll")                                                      \
        for (int ni = 0; ni < 4; ni++)                                         \
          acc[mi][ni] = __builtin_amdgcn_mfma_f32_16x16x32_bf16(               \
              a[mi], b[ni], acc[mi][ni], 0, 0, 0);                             \
    }                                                                          \
  }

// ---------------------------------------------------------------------------
// GEMM: out[M=8192][1024] = A(bf16) @ W + bias (+ res). BT = W^T bf16 [n][k].
// OUTMODE: 0 = f32 row-major, 1 = bf16 row-major.
// ---------------------------------------------------------------------------
template <int RESID, int OUTMODE>
__global__ __launch_bounds__(256) void gemm_bt(
    const __bf16* __restrict__ A, const __bf16* __restrict__ BT,
    const float* __restrict__ bias, const float* __restrict__ res,
    float* __restrict__ outF, __bf16* __restrict__ outB)
{
  __shared__ __bf16 As[2 * 128 * 64];
  __shared__ __bf16 Bs[2 * 128 * 64];
  int t0 = threadIdx.x;
  int lane = t0 & 63, w = t0 >> 6;
  int wr = w >> 1, wc = w & 1;
  int fr = lane & 15, fq = lane >> 4;
  int orig = blockIdx.x;
  int bid = (orig & 7) * 64 + (orig >> 3);  // XCD-chunked, 512 % 8 == 0
  int bm = bid >> 3, bn = bid & 7;

  f32x4 acc[4][4] = {};

  int srow = t0 >> 3, sg = t0 & 7;
  int sgx = sg ^ (srow & 7);
  const __bf16* Ag = A  + (size_t)(bm * 128 + srow) * 1024 + sgx * 8;
  const __bf16* Bg = BT + (size_t)(bn * 128 + srow) * 1024 + sgx * 8;

  GEMM_KLOOP64(acc)

#pragma unroll
  for (int ni = 0; ni < 4; ni++) {
    int col = bn * 128 + wc * 64 + ni * 16 + fr;
    float bcol = bias[col];
#pragma unroll
    for (int mi = 0; mi < 4; mi++) {
      int row0 = bm * 128 + wr * 64 + mi * 16 + fq * 4;
#pragma unroll
      for (int r = 0; r < 4; r++) {
        size_t idx = (size_t)(row0 + r) * 1024 + col;
        float v = acc[mi][ni][r] + bcol;
        if constexpr (RESID) v += res[idx];
        if constexpr (OUTMODE == 1) outB[idx] = (__bf16)v;
        else                        outF[idx] = v;
      }
    }
  }
}

// ---------------------------------------------------------------------------
// Fused QKV GEMM (R9 version): A[8192][1024] @ WTqkv^T (N=3072). bn 0-7 -> Q
// (pre-scaled by SCQ), 8-15 -> K, 16-23 -> V (VT[b][h][dd][s]).
// ---------------------------------------------------------------------------
__global__ __launch_bounds__(256) void gemm_qkv(
    const __bf16* __restrict__ A, const __bf16* __restrict__ BT,
    const float* __restrict__ bq, const float* __restrict__ bk,
    const float* __restrict__ bv,
    __bf16* __restrict__ Qo, __bf16* __restrict__ Ko, __bf16* __restrict__ VTo)
{
  __shared__ __bf16 As[2 * 128 * 64];
  __shared__ __bf16 Bs[2 * 128 * 64];
  int t0 = threadIdx.x;
  int lane = t0 & 63, w = t0 >> 6;
  int wr = w >> 1, wc = w & 1;
  int fr = lane & 15, fq = lane >> 4;
  int orig = blockIdx.x;
  int bid = (orig & 7) * 192 + (orig >> 3);  // 1536 % 8 == 0
  int bm = bid / 24, bn = bid % 24;

  f32x4 acc[4][4] = {};

  int srow = t0 >> 3, sg = t0 & 7;
  int sgx = sg ^ (srow & 7);
  const __bf16* Ag = A  + (size_t)(bm * 128 + srow) * 1024 + sgx * 8;
  const __bf16* Bg = BT + (size_t)(bn * 128 + srow) * 1024 + sgx * 8;

  GEMM_KLOOP64(acc)

#pragma unroll
  for (int ni = 0; ni < 4; ni++) {
    int col3 = bn * 128 + wc * 64 + ni * 16 + fr;
#pragma unroll
    for (int mi = 0; mi < 4; mi++) {
      int row0 = bm * 128 + wr * 64 + mi * 16 + fq * 4;
      if (bn < 8) {               // Q, pre-scaled
        float bcol = bq[col3];
#pragma unroll
        for (int r = 0; r < 4; r++)
          Qo[(size_t)(row0 + r) * 1024 + col3] = (__bf16)((acc[mi][ni][r] + bcol) * SCQ);
      } else if (bn < 16) {       // K
        int c = col3 - 1024;
        float bcol = bk[c];
#pragma unroll
        for (int r = 0; r < 4; r++)
          Ko[(size_t)(row0 + r) * 1024 + c] = (__bf16)(acc[mi][ni][r] + bcol);
      } else {                    // V -> VT[b][h][dd][s], rows are s-contig
        int c = col3 - 2048;
        float bcol = bv[c];
        int b_ = row0 >> 11, s0 = row0 & 2047;
        size_t idx = ((size_t)((b_ * 16 + (c >> 6)) * 64 + (c & 63))) * 2048 + s0;
        bf16x4 o4;
#pragma unroll
        for (int r = 0; r < 4; r++) o4[r] = (__bf16)(acc[mi][ni][r] + bcol);
        *(bf16x4*)&VTo[idx] = o4;
      }
    }
  }
}

// ---------------------------------------------------------------------------
// Flash attention, NO LDS staging: kf/vb fragments read directly from
// global (L1/L2-backed; per-XCD working set = 8 bh x 512KB = 4MB = L2).
// Swapped-QK^T 32x32, 2 q-groups/wave, grid = 512 blocks x 4 waves.
// No barriers in the K-loop; vb loads issued before softmax so their
// latency hides under the exp2/cvt_pk VALU phase.
// Q arrives pre-scaled by log2(e)/8 -> exp2(s) directly, no max-sub.
// ---------------------------------------------------------------------------
__global__ __launch_bounds__(256, 2) void attn_fwd(
    const __bf16* __restrict__ Q, const __bf16* __restrict__ K,
    const __bf16* __restrict__ VT, __bf16* __restrict__ O)
{
  int orig = blockIdx.x;
  int bid = (orig & 7) * 64 + (orig >> 3);   // XCD-bijective: 512 % 8 == 0
  int bh = bid >> 3, qt = bid & 7;
  int h = bh & 15, b = bh >> 4;
  int t = threadIdx.x, lane = t & 63, w = t >> 6;
  int ql = lane & 31, hi = lane >> 5;
  size_t tokBase = (size_t)b * 2048;
  int colBase = h * 64;

  __shared__ float lsm[4][2][32];

  // Q fragments: group g, lane holds Q[q = qt*256 + w*64 + g*32 + ql][d=c*16+hi*8+i]
  bf16x8 qf[2][4];
#pragma unroll
  for (int g = 0; g < 2; g++) {
    const __bf16* qrow = Q + (tokBase + qt * 256 + w * 64 + g * 32 + ql) * 1024 + colBase + hi * 8;
#pragma unroll
    for (int c = 0; c < 4; c++) qf[g][c] = *(const bf16x8*)(qrow + c * 16);
  }

  f32x16 oacc[2][2] = {};
  float2 lsum2[2] = {};

  // direct-global fragment base pointers (lane-resolved rows)
  const __bf16* Kg0 = K + (tokBase + ql) * 1024 + colBase + hi * 8;        // kj = ql
  const __bf16* Kg1 = K + (tokBase + 32 + ql) * 1024 + colBase + hi * 8;   // kj = 32+ql
  const __bf16* Vg0 = VT + ((size_t)bh * 64 + ql) * 2048 + hi * 8;         // d = ql
  const __bf16* Vg1 = VT + ((size_t)bh * 64 + 32 + ql) * 2048 + hi * 8;    // d = 32+ql

  for (int kt = 0; kt < 32; ++kt) {
    int kb = kt * 64;

    // ---- kf loads (8 x bf16x8 from L1/L2) ----
    bf16x8 kf0[4], kf1[4];
#pragma unroll
    for (int c = 0; c < 4; c++) {
      kf0[c] = *(const bf16x8*)(Kg0 + (size_t)kb * 1024 + c * 16);
      kf1[c] = *(const bf16x8*)(Kg1 + (size_t)kb * 1024 + c * 16);
    }

    // ---- S^T = K.Q^T: kf shared by both q-groups ----
    f32x16 s_[2][2] = {};
    __builtin_amdgcn_s_setprio(1);
#pragma unroll
    for (int c = 0; c < 4; c++) {
#pragma unroll
      for (int g = 0; g < 2; g++) {
        s_[g][0] = __builtin_amdgcn_mfma_f32_32x32x16_bf16(kf0[c], qf[g][c], s_[g][0], 0, 0, 0);
        s_[g][1] = __builtin_amdgcn_mfma_f32_32x32x16_bf16(kf1[c], qf[g][c], s_[g][1], 0, 0, 0);
      }
    }
    __builtin_amdgcn_s_setprio(0);

    // ---- issue vb loads NOW (latency hides under softmax VALU) ----
    // vb[dh][h32*2+kc] elem j = VT[bh][dh*32+ql][kb + (h32*4+kc*2+hi)*8 + j]
    bf16x8 vb[2][4];
#pragma unroll
    for (int h32 = 0; h32 < 2; h32++)
#pragma unroll
      for (int kc = 0; kc < 2; kc++) {
        int off = kb + (h32 * 4 + kc * 2) * 8;
        vb[0][h32 * 2 + kc] = *(const bf16x8*)(Vg0 + off);
        vb[1][h32 * 2 + kc] = *(const bf16x8*)(Vg1 + off);
      }

    // ---- softmax per group (Q pre-scaled, no max-sub) -> P A-fragments ----
    unsigned int pa[2][2][2][4];
#pragma unroll
    for (int g = 0; g < 2; g++) {
#pragma unroll
      for (int h32 = 0; h32 < 2; h32++) {
        float p[16];
#pragma unroll
        for (int r = 0; r < 16; r++)
          p[r] = __builtin_amdgcn_exp2f(s_[g][h32][r]);
#pragma unroll
        for (int i = 0; i < 8; i++) {
          lsum2[g].x += p[2 * i];
          lsum2[g].y += p[2 * i + 1];
        }
        unsigned int cw[8];
#pragma unroll
        for (int i = 0; i < 8; i++) {
          unsigned int d_;
          asm("v_cvt_pk_bf16_f32 %0, %1, %2" : "=v"(d_) : "v"(p[2 * i]), "v"(p[2 * i + 1]));
          cw[i] = d_;
        }
        asm("v_permlane32_swap_b32 %0, %1" : "+v"(cw[2]), "+v"(cw[0]));
        asm("v_permlane32_swap_b32 %0, %1" : "+v"(cw[3]), "+v"(cw[1]));
        asm("v_permlane32_swap_b32 %0, %1" : "+v"(cw[6]), "+v"(cw[4]));
        asm("v_permlane32_swap_b32 %0, %1" : "+v"(cw[7]), "+v"(cw[5]));
        pa[g][h32][0][0] = cw[0]; pa[g][h32][0][1] = cw[1];
        pa[g][h32][0][2] = cw[2]; pa[g][h32][0][3] = cw[3];
        pa[g][h32][1][0] = cw[4]; pa[g][h32][1][1] = cw[5];
        pa[g][h32][1][2] = cw[6]; pa[g][h32][1][3] = cw[7];
      }
    }

    // ---- PV: vb shared by both q-groups ----
    __builtin_amdgcn_s_setprio(1);
#pragma unroll
    for (int dh = 0; dh < 2; dh++)
#pragma unroll
      for (int g = 0; g < 2; g++)
#pragma unroll
        for (int h32 = 0; h32 < 2; h32++)
#pragma unroll
          for (int kc = 0; kc < 2; kc++) {
            union { unsigned int u[4]; bf16x8 v; } A;
            A.u[0] = pa[g][h32][kc][0]; A.u[1] = pa[g][h32][kc][1];
            A.u[2] = pa[g][h32][kc][2]; A.u[3] = pa[g][h32][kc][3];
            oacc[g][dh] = __builtin_amdgcn_mfma_f32_32x32x16_bf16(A.v, vb[dh][h32 * 2 + kc], oacc[g][dh], 0, 0, 0);
          }
    __builtin_amdgcn_s_setprio(0);
  }

  // ---- epilogue: divide by per-row l, write ----
#pragma unroll
  for (int g = 0; g < 2; g++) {
    float ls = lsum2[g].x + lsum2[g].y;
    float ltot = ls + __shfl_xor(ls, 32);
    if (hi == 0) lsm[w][g][ql] = ltot;
  }
  __syncthreads();
#pragma unroll
  for (int g = 0; g < 2; g++) {
    float rl[16];
#pragma unroll
    for (int r = 0; r < 16; r++)
      rl[r] = 1.0f / lsm[w][g][(r & 3) + 8 * (r >> 2) + 4 * hi];
    size_t obase = tokBase + qt * 256 + w * 64 + g * 32;
#pragma unroll
    for (int dh = 0; dh < 2; dh++)
#pragma unroll
      for (int r = 0; r < 16; r++) {
        int qrw = (r & 3) + 8 * (r >> 2) + 4 * hi;
        O[(obase + qrw) * 1024 + colBase + dh * 32 + ql] = (__bf16)(oacc[g][dh][r] * rl[r]);
      }
  }
}

// ---------------------------------------------------------------------------
extern "C" void kernel_launch(void* const* d_in, const int* in_sizes, int n_in,
                              void* d_out, int out_size, void* d_ws, size_t ws_size,
                              hipStream_t stream)
{
  const float* x         = (const float*)d_in[0];
  const float* rbb_ln_g  = (const float*)d_in[2];
  const float* rbb_ln_b  = (const float*)d_in[3];
  const float* rbb_W     = (const float*)d_in[4];
  const float* rbb_b     = (const float*)d_in[5];
  const float* rba_ln_g  = (const float*)d_in[6];
  const float* rba_ln_b  = (const float*)d_in[7];
  const float* rba_W     = (const float*)d_in[8];
  const float* rba_b     = (const float*)d_in[9];
  const float* attn_ln_g = (const float*)d_in[10];
  const float* attn_ln_b = (const float*)d_in[11];
  const float* Wq = (const float*)d_in[12];
  const float* bq = (const float*)d_in[13];
  const float* Wk = (const float*)d_in[14];
  const float* bk = (const float*)d_in[15];
  const float* Wv = (const float*)d_in[16];
  const float* bv = (const float*)d_in[17];
  const float* Wo = (const float*)d_in[18];
  const float* bo = (const float*)d_in[19];

  char* ws = (char*)d_ws;
  float*  X   = (float*)(ws);                     // 33.5 MB residual stream
  __bf16* Tb  = (__bf16*)(ws + 33554432);         // bf16 T (aliases Q region)
  __bf16* Qbf = (__bf16*)(ws + 33554432);
  __bf16* Kbf = (__bf16*)(ws + 33554432 + 16777216);
  __bf16* Abf = (__bf16*)(ws + 67108864);         // LN output
  __bf16* VT  = (__bf16*)(ws + 83886080);         // [4][16][64][2048] bf16
  __bf16* Cbf = (__bf16*)(ws + 100663296);        // attn output
  __bf16* Wbf = (__bf16*)(ws + 117440512);        // 24 weight matrices (48MB)
  auto WT = [&](int m) { return Wbf + (size_t)m * 1048576; };

  float* outF = (float*)d_out;
  dim3 blk(256);

  wt_conv<<<24 * 1024, blk, 0, stream>>>(rbb_W, Wq, Wk, Wv, Wo, rba_W, Wbf);

  // rbb resnet
  for (int i = 0; i < 2; i++) {
    const float* xin = (i == 0) ? x : X;
    ln_relu<0><<<8192, blk, 0, stream>>>(xin, rbb_ln_g + (i * 2 + 0) * 1024, rbb_ln_b + (i * 2 + 0) * 1024, Abf);
    gemm_bt<0, 1><<<512, blk, 0, stream>>>(Abf, WT(i * 2 + 0), rbb_b + (i * 2 + 0) * 1024, nullptr, nullptr, Tb);
    ln_relu<1><<<8192, blk, 0, stream>>>(Tb, rbb_ln_g + (i * 2 + 1) * 1024, rbb_ln_b + (i * 2 + 1) * 1024, Abf);
    gemm_bt<1, 0><<<512, blk, 0, stream>>>(Abf, WT(i * 2 + 1), rbb_b + (i * 2 + 1) * 1024, xin, X, nullptr);
  }

  // attention layers (fused QKV projection)
  for (int l = 0; l < 4; l++) {
    ln_relu<0><<<8192, blk, 0, stream>>>(X, attn_ln_g + l * 1024, attn_ln_b + l * 1024, Abf);
    gemm_qkv<<<1536, blk, 0, stream>>>(Abf, WT(4 + 3 * l),
                                       bq + l * 1024, bk + l * 1024, bv + l * 1024,
                                       Qbf, Kbf, VT);
    attn_fwd<<<512, blk, 0, stream>>>(Qbf, Kbf, VT, Cbf);
    gemm_bt<1, 0><<<512, blk, 0, stream>>>(Cbf, WT(16 + l), bo + l * 1024, X, X, nullptr);
  }

  // rba resnet (last GEMM writes d_out directly)
  for (int i = 0; i < 2; i++) {
    ln_relu<0><<<8192, blk, 0, stream>>>(X, rba_ln_g + (i * 2 + 0) * 1024, rba_ln_b + (i * 2 + 0) * 1024, Abf);
    gemm_bt<0, 1><<<512, blk, 0, stream>>>(Abf, WT(20 + i * 2 + 0), rba_b + (i * 2 + 0) * 1024, nullptr, nullptr, Tb);
    ln_relu<1><<<8192, blk, 0, stream>>>(Tb, rba_ln_g + (i * 2 + 1) * 1024, rba_ln_b + (i * 2 + 1) * 1024, Abf);
    float* dst = (i == 1) ? outF : X;
    gemm_bt<1, 0><<<512, blk, 0, stream>>>(Abf, WT(20 + i * 2 + 1), rba_b + (i * 2 + 1) * 1024, X, dst, nullptr);
  }
}

// Round 14
// 1032.110 us; speedup vs baseline: 1.1989x; 1.1989x over previous
//
#include <hip/hip_runtime.h>

// ---------------------------------------------------------------------------
// Transformer: rbb resnet (2 blocks) -> 4 attention layers -> rba resnet.
// Round 14: attention reverted to R9 (R13 direct-global exposed L2 latency:
// 86->134us — LDS staging earns its cost). NEW: residual stream X stored
// bf16 (dtype-only change, ~150MB HBM saved across 21 dispatches). Input x
// stays f32 for the first LN + first residual; final GEMM writes f32 d_out.
// ---------------------------------------------------------------------------

typedef __bf16 bf16x8 __attribute__((ext_vector_type(8)));
typedef __bf16 bf16x4 __attribute__((ext_vector_type(4)));
typedef float  f32x4  __attribute__((ext_vector_type(4)));
typedef float  f32x16 __attribute__((ext_vector_type(16)));

#define SCQ 0.18033688011112042f   // log2(e)/8, folded into Q projection

__device__ __forceinline__ void gl_lds16(const void* g, void* l) {
  __builtin_amdgcn_global_load_lds(
      (const __attribute__((address_space(1))) void*)g,
      (__attribute__((address_space(3))) void*)l, 16, 0, 0);
}

// ---------------------------------------------------------------------------
// Weight convert+transpose: W f32 [1024][1024] -> WT bf16 [n][k].
// Order: 0-3 rbb, 4..15 per-layer QKV (Wq|Wk|Wv contiguous), 16-19 Wo,
// 20-23 rba.
// ---------------------------------------------------------------------------
__global__ __launch_bounds__(256) void wt_conv(
    const float* __restrict__ rbbW, const float* __restrict__ Wq,
    const float* __restrict__ Wk,   const float* __restrict__ Wv,
    const float* __restrict__ Wo,   const float* __restrict__ rbaW,
    __bf16* __restrict__ out)
{
  int bid = blockIdx.x;
  int m = bid >> 10;
  int tile = bid & 1023;
  int tr = tile >> 5, tc = tile & 31;
  const float* src;
  if (m < 4)       src = rbbW + (size_t)m * 1048576;
  else if (m < 16) {
    int l = (m - 4) / 3, r = (m - 4) % 3;
    const float* w3 = (r == 0) ? Wq : (r == 1) ? Wk : Wv;
    src = w3 + (size_t)l * 1048576;
  }
  else if (m < 20) src = Wo   + (size_t)(m - 16) * 1048576;
  else             src = rbaW + (size_t)(m - 20) * 1048576;
  __bf16* dst = out + (size_t)m * 1048576;

  __shared__ float tileS[32][33];
  int tx = threadIdx.x & 31, ty = threadIdx.x >> 5;
#pragma unroll
  for (int i = 0; i < 32; i += 8)
    tileS[ty + i][tx] = src[(size_t)(tr * 32 + ty + i) * 1024 + tc * 32 + tx];
  __syncthreads();
#pragma unroll
  for (int i = 0; i < 32; i += 8)
    dst[(size_t)(tc * 32 + ty + i) * 1024 + tr * 32 + tx] = (__bf16)tileS[tx][ty + i];
}

// ---------------------------------------------------------------------------
// LayerNorm + ReLU, [row][1024] -> bf16 [row][1024]. INBF: input dtype.
// ---------------------------------------------------------------------------
template <int INBF>
__global__ __launch_bounds__(256) void ln_relu(
    const void* __restrict__ inv, const float* __restrict__ g,
    const float* __restrict__ bta, __bf16* __restrict__ out)
{
  int row = blockIdx.x;
  int t = threadIdx.x;
  float4 v;
  if constexpr (INBF) {
    bf16x4 b4 = ((const bf16x4*)((const __bf16*)inv + (size_t)row * 1024))[t];
    v = make_float4((float)b4[0], (float)b4[1], (float)b4[2], (float)b4[3]);
  } else {
    v = ((const float4*)((const float*)inv + (size_t)row * 1024))[t];
  }
  float s  = v.x + v.y + v.z + v.w;
  float s2 = v.x * v.x + v.y * v.y + v.z * v.z + v.w * v.w;
#pragma unroll
  for (int o = 32; o > 0; o >>= 1) {
    s  += __shfl_xor(s, o);
    s2 += __shfl_xor(s2, o);
  }
  __shared__ float rs[4], rs2[4];
  int w = t >> 6, lane = t & 63;
  if (lane == 0) { rs[w] = s; rs2[w] = s2; }
  __syncthreads();
  s  = rs[0] + rs[1] + rs[2] + rs[3];
  s2 = rs2[0] + rs2[1] + rs2[2] + rs2[3];
  float mu  = s * (1.0f / 1024.0f);
  float var = s2 * (1.0f / 1024.0f) - mu * mu;
  float ri  = rsqrtf(var + 1e-5f);
  float4 gv = ((const float4*)g)[t];
  float4 bv = ((const float4*)bta)[t];
  float y0 = fmaxf(0.f, (v.x - mu) * ri * gv.x + bv.x);
  float y1 = fmaxf(0.f, (v.y - mu) * ri * gv.y + bv.y);
  float y2 = fmaxf(0.f, (v.z - mu) * ri * gv.z + bv.z);
  float y3 = fmaxf(0.f, (v.w - mu) * ri * gv.w + bv.w);
  bf16x4 o4 = { (__bf16)y0, (__bf16)y1, (__bf16)y2, (__bf16)y3 };
  *(bf16x4*)(out + (size_t)row * 1024 + t * 4) = o4;
}

// ---------------------------------------------------------------------------
// GEMM K-loop BK=64: 128x128 tile, 2-buffer, counted vmcnt(8), raw barriers.
// LDS [row][64] with 16B-group XOR swizzle g^(row&7), source-pre-swizzled.
// ---------------------------------------------------------------------------
#define STAGE8(k0, nb)                                                         \
  {                                                                            \
    const __bf16* Ak = Ag + (k0);                                              \
    const __bf16* Bk = Bg + (k0);                                              \
    char* Ad = (char*)As + (nb) * 16384 + w * 1024;                            \
    char* Bd = (char*)Bs + (nb) * 16384 + w * 1024;                            \
    gl_lds16(Ak,         Ad);                                                  \
    gl_lds16(Ak + 32768, Ad + 4096);                                           \
    gl_lds16(Ak + 65536, Ad + 8192);                                           \
    gl_lds16(Ak + 98304, Ad + 12288);                                          \
    gl_lds16(Bk,         Bd);                                                  \
    gl_lds16(Bk + 32768, Bd + 4096);                                           \
    gl_lds16(Bk + 65536, Bd + 8192);                                           \
    gl_lds16(Bk + 98304, Bd + 12288);                                          \
  }

#define GEMM_KLOOP64(acc)                                                      \
  STAGE8(0, 0)                                                                 \
  for (int t = 0; t < 16; ++t) {                                               \
    __builtin_amdgcn_s_barrier();                                              \
    if (t < 15) {                                                              \
      STAGE8((t + 1) * 64, (t + 1) & 1)                                        \
      asm volatile("s_waitcnt vmcnt(8)" ::: "memory");                         \
    } else {                                                                   \
      asm volatile("s_waitcnt vmcnt(0)" ::: "memory");                         \
    }                                                                          \
    __builtin_amdgcn_s_barrier();                                              \
    const __bf16* Asb = As + (t & 1) * 8192;                                   \
    const __bf16* Bsb = Bs + (t & 1) * 8192;                                   \
    _Pragma("unroll")                                                          \
    for (int kk = 0; kk < 2; kk++) {                                           \
      bf16x8 a[4], b[4];                                                       \
      _Pragma("unroll")                                                        \
      for (int mi = 0; mi < 4; mi++)                                           \
        a[mi] = *(const bf16x8*)&Asb[(wr * 64 + mi * 16 + fr) * 64 +           \
                                     (((kk * 4 + fq) ^ (fr & 7)) * 8)];        \
      _Pragma("unroll")                                                        \
      for (int ni = 0; ni < 4; ni++)                                           \
        b[ni] = *(const bf16x8*)&Bsb[(wc * 64 + ni * 16 + fr) * 64 +           \
                                     (((kk * 4 + fq) ^ (fr & 7)) * 8)];        \
      _Pragma("unroll")                                                        \
      for (int mi = 0; mi < 4; mi++)                                           \
        _Pragma("unroll")                                                      \
        for (int ni = 0; ni < 4; ni++)                                         \
          acc[mi][ni] = __builtin_amdgcn_mfma_f32_16x16x32_bf16(               \
              a[mi], b[ni], acc[mi][ni], 0, 0, 0);                             \
    }                                                                          \
  }

// ---------------------------------------------------------------------------
// GEMM: out[M=8192][1024] = A(bf16) @ W + bias (+ res). BT = W^T bf16 [n][k].
// RESID: 0 = none, 1 = f32 residual, 2 = bf16 residual.
// OUTMODE: 0 = f32 row-major, 1 = bf16 row-major.
// ---------------------------------------------------------------------------
template <int RESID, int OUTMODE>
__global__ __launch_bounds__(256) void gemm_bt(
    const __bf16* __restrict__ A, const __bf16* __restrict__ BT,
    const float* __restrict__ bias, const void* __restrict__ resv,
    float* __restrict__ outF, __bf16* __restrict__ outB)
{
  __shared__ __bf16 As[2 * 128 * 64];
  __shared__ __bf16 Bs[2 * 128 * 64];
  int t0 = threadIdx.x;
  int lane = t0 & 63, w = t0 >> 6;
  int wr = w >> 1, wc = w & 1;
  int fr = lane & 15, fq = lane >> 4;
  int orig = blockIdx.x;
  int bid = (orig & 7) * 64 + (orig >> 3);  // XCD-chunked, 512 % 8 == 0
  int bm = bid >> 3, bn = bid & 7;

  f32x4 acc[4][4] = {};

  int srow = t0 >> 3, sg = t0 & 7;
  int sgx = sg ^ (srow & 7);
  const __bf16* Ag = A  + (size_t)(bm * 128 + srow) * 1024 + sgx * 8;
  const __bf16* Bg = BT + (size_t)(bn * 128 + srow) * 1024 + sgx * 8;

  GEMM_KLOOP64(acc)

#pragma unroll
  for (int ni = 0; ni < 4; ni++) {
    int col = bn * 128 + wc * 64 + ni * 16 + fr;
    float bcol = bias[col];
#pragma unroll
    for (int mi = 0; mi < 4; mi++) {
      int row0 = bm * 128 + wr * 64 + mi * 16 + fq * 4;
#pragma unroll
      for (int r = 0; r < 4; r++) {
        size_t idx = (size_t)(row0 + r) * 1024 + col;
        float v = acc[mi][ni][r] + bcol;
        if constexpr (RESID == 1) v += ((const float*)resv)[idx];
        if constexpr (RESID == 2) v += (float)((const __bf16*)resv)[idx];
        if constexpr (OUTMODE == 1) outB[idx] = (__bf16)v;
        else                        outF[idx] = v;
      }
    }
  }
}

// ---------------------------------------------------------------------------
// Fused QKV GEMM (R9 version): A[8192][1024] @ WTqkv^T (N=3072). bn 0-7 -> Q
// (pre-scaled by SCQ), 8-15 -> K, 16-23 -> V (VT[b][h][dd][s]).
// ---------------------------------------------------------------------------
__global__ __launch_bounds__(256) void gemm_qkv(
    const __bf16* __restrict__ A, const __bf16* __restrict__ BT,
    const float* __restrict__ bq, const float* __restrict__ bk,
    const float* __restrict__ bv,
    __bf16* __restrict__ Qo, __bf16* __restrict__ Ko, __bf16* __restrict__ VTo)
{
  __shared__ __bf16 As[2 * 128 * 64];
  __shared__ __bf16 Bs[2 * 128 * 64];
  int t0 = threadIdx.x;
  int lane = t0 & 63, w = t0 >> 6;
  int wr = w >> 1, wc = w & 1;
  int fr = lane & 15, fq = lane >> 4;
  int orig = blockIdx.x;
  int bid = (orig & 7) * 192 + (orig >> 3);  // 1536 % 8 == 0
  int bm = bid / 24, bn = bid % 24;

  f32x4 acc[4][4] = {};

  int srow = t0 >> 3, sg = t0 & 7;
  int sgx = sg ^ (srow & 7);
  const __bf16* Ag = A  + (size_t)(bm * 128 + srow) * 1024 + sgx * 8;
  const __bf16* Bg = BT + (size_t)(bn * 128 + srow) * 1024 + sgx * 8;

  GEMM_KLOOP64(acc)

#pragma unroll
  for (int ni = 0; ni < 4; ni++) {
    int col3 = bn * 128 + wc * 64 + ni * 16 + fr;
#pragma unroll
    for (int mi = 0; mi < 4; mi++) {
      int row0 = bm * 128 + wr * 64 + mi * 16 + fq * 4;
      if (bn < 8) {               // Q, pre-scaled
        float bcol = bq[col3];
#pragma unroll
        for (int r = 0; r < 4; r++)
          Qo[(size_t)(row0 + r) * 1024 + col3] = (__bf16)((acc[mi][ni][r] + bcol) * SCQ);
      } else if (bn < 16) {       // K
        int c = col3 - 1024;
        float bcol = bk[c];
#pragma unroll
        for (int r = 0; r < 4; r++)
          Ko[(size_t)(row0 + r) * 1024 + c] = (__bf16)(acc[mi][ni][r] + bcol);
      } else {                    // V -> VT[b][h][dd][s], rows are s-contig
        int c = col3 - 2048;
        float bcol = bv[c];
        int b_ = row0 >> 11, s0 = row0 & 2047;
        size_t idx = ((size_t)((b_ * 16 + (c >> 6)) * 64 + (c & 63))) * 2048 + s0;
        bf16x4 o4;
#pragma unroll
        for (int r = 0; r < 4; r++) o4[r] = (__bf16)(acc[mi][ni][r] + bcol);
        *(bf16x4*)&VTo[idx] = o4;
      }
    }
  }
}

// ---------------------------------------------------------------------------
// Flash attention (R9 verified kernel). Swapped-QK^T 32x32, 2 q-groups per
// wave (64 q-rows/wave). Grid = 64 bh * 8 qtiles = 512 blocks, 4 waves.
// Each kf LDS read feeds 2 MFMAs (both q-groups); each vb read feeds 2.
// Q arrives pre-scaled by log2(e)/8 -> exp2(s) directly, no max-sub.
// ---------------------------------------------------------------------------
__global__ __launch_bounds__(256, 2) void attn_fwd(
    const __bf16* __restrict__ Q, const __bf16* __restrict__ K,
    const __bf16* __restrict__ VT, __bf16* __restrict__ O)
{
  int orig = blockIdx.x;
  int bid = (orig & 7) * 64 + (orig >> 3);   // XCD-bijective: 512 % 8 == 0
  int bh = bid >> 3, qt = bid & 7;
  int h = bh & 15, b = bh >> 4;
  int t = threadIdx.x, lane = t & 63, w = t >> 6;
  int ql = lane & 31, hi = lane >> 5;
  size_t tokBase = (size_t)b * 2048;
  int colBase = h * 64;

  __shared__ __bf16 Ks[2 * 64 * 64];   // dbuf [kj][64d], source-XOR-swizzled
  __shared__ __bf16 VTs[2 * 64 * 64];  // dbuf [d][64kj], source-XOR-swizzled
  __shared__ float  lsm[4][2][32];

  // Q fragments: group g, lane holds Q[q = qt*256 + w*64 + g*32 + ql][d=c*16+hi*8+i]
  bf16x8 qf[2][4];
#pragma unroll
  for (int g = 0; g < 2; g++) {
    const __bf16* qrow = Q + (tokBase + qt * 256 + w * 64 + g * 32 + ql) * 1024 + colBase + hi * 8;
#pragma unroll
    for (int c = 0; c < 4; c++) qf[g][c] = *(const bf16x8*)(qrow + c * 16);
  }

  f32x16 oacc[2][2] = {};
  float2 lsum2[2] = {};

  // staging: wave w stages rows w*8..w*8+7 (+32), XOR-swizzled source cols
  int srow = w * 8 + (lane >> 3);
  int sgc  = (lane & 7) ^ (lane >> 3);
  const __bf16* kSrc = K + (tokBase + srow) * 1024 + colBase + sgc * 8;
  const __bf16* vtSrc = VT + ((size_t)bh * 64 + srow) * 2048 + sgc * 8;
  char* kDst = (char*)Ks + w * 1024;
  char* vtDst = (char*)VTs + w * 1024;

  // prologue: stage tile 0 into buf 0
  gl_lds16(kSrc,              kDst);
  gl_lds16(kSrc + 32 * 1024,  kDst + 4096);
  gl_lds16(vtSrc,             vtDst);
  gl_lds16(vtSrc + 32 * 2048, vtDst + 4096);
  kSrc += 64 * 1024; vtSrc += 64;
  __syncthreads();

  for (int kt = 0; kt < 32; ++kt) {
    if (kt + 1 < 32) {           // stage next tile into other buffer
      int nb = (kt + 1) & 1;
      gl_lds16(kSrc,              kDst + nb * 8192);
      gl_lds16(kSrc + 32 * 1024,  kDst + nb * 8192 + 4096);
      gl_lds16(vtSrc,             vtDst + nb * 8192);
      gl_lds16(vtSrc + 32 * 2048, vtDst + nb * 8192 + 4096);
      kSrc += 64 * 1024; vtSrc += 64;
    }
    const __bf16* Ksb  = Ks  + (kt & 1) * 4096;
    const __bf16* VTsb = VTs + (kt & 1) * 4096;

    // ---- S^T = K.Q^T: kf reads shared by both q-groups ----
    f32x16 s_[2][2] = {};
    __builtin_amdgcn_s_setprio(1);
#pragma unroll
    for (int c = 0; c < 4; c++) {
      int g2 = c * 2 + hi;
      bf16x8 kf0 = *(const bf16x8*)&Ksb[ql * 64 + ((g2 ^ (ql & 7)) * 8)];
      bf16x8 kf1 = *(const bf16x8*)&Ksb[(32 + ql) * 64 + ((g2 ^ (ql & 7)) * 8)];
#pragma unroll
      for (int g = 0; g < 2; g++) {
        s_[g][0] = __builtin_amdgcn_mfma_f32_32x32x16_bf16(kf0, qf[g][c], s_[g][0], 0, 0, 0);
        s_[g][1] = __builtin_amdgcn_mfma_f32_32x32x16_bf16(kf1, qf[g][c], s_[g][1], 0, 0, 0);
      }
    }
    __builtin_amdgcn_s_setprio(0);

    // ---- softmax per group (Q pre-scaled, no max-sub) -> P A-fragments ----
    unsigned int pa[2][2][2][4];
#pragma unroll
    for (int g = 0; g < 2; g++) {
#pragma unroll
      for (int h32 = 0; h32 < 2; h32++) {
        float p[16];
#pragma unroll
        for (int r = 0; r < 16; r++)
          p[r] = __builtin_amdgcn_exp2f(s_[g][h32][r]);
#pragma unroll
        for (int i = 0; i < 8; i++) {
          lsum2[g].x += p[2 * i];
          lsum2[g].y += p[2 * i + 1];
        }
        unsigned int cw[8];
#pragma unroll
        for (int i = 0; i < 8; i++) {
          unsigned int d_;
          asm("v_cvt_pk_bf16_f32 %0, %1, %2" : "=v"(d_) : "v"(p[2 * i]), "v"(p[2 * i + 1]));
          cw[i] = d_;
        }
        asm("v_permlane32_swap_b32 %0, %1" : "+v"(cw[2]), "+v"(cw[0]));
        asm("v_permlane32_swap_b32 %0, %1" : "+v"(cw[3]), "+v"(cw[1]));
        asm("v_permlane32_swap_b32 %0, %1" : "+v"(cw[6]), "+v"(cw[4]));
        asm("v_permlane32_swap_b32 %0, %1" : "+v"(cw[7]), "+v"(cw[5]));
        pa[g][h32][0][0] = cw[0]; pa[g][h32][0][1] = cw[1];
        pa[g][h32][0][2] = cw[2]; pa[g][h32][0][3] = cw[3];
        pa[g][h32][1][0] = cw[4]; pa[g][h32][1][1] = cw[5];
        pa[g][h32][1][2] = cw[6]; pa[g][h32][1][3] = cw[7];
      }
    }

    // ---- PV: vb reads shared by both q-groups ----
#pragma unroll
    for (int dh = 0; dh < 2; dh++) {
      int drow = dh * 32 + ql;
      int dsw = drow & 7;
      bf16x8 vb[4];
#pragma unroll
      for (int h32 = 0; h32 < 2; h32++)
#pragma unroll
        for (int kc = 0; kc < 2; kc++) {
          int g2 = h32 * 4 + kc * 2 + hi;  // kj group = g2*8
          vb[h32 * 2 + kc] = *(const bf16x8*)&VTsb[drow * 64 + ((g2 ^ dsw) * 8)];
        }
      __builtin_amdgcn_s_setprio(1);
#pragma unroll
      for (int g = 0; g < 2; g++)
#pragma unroll
        for (int h32 = 0; h32 < 2; h32++)
#pragma unroll
          for (int kc = 0; kc < 2; kc++) {
            union { unsigned int u[4]; bf16x8 v; } A;
            A.u[0] = pa[g][h32][kc][0]; A.u[1] = pa[g][h32][kc][1];
            A.u[2] = pa[g][h32][kc][2]; A.u[3] = pa[g][h32][kc][3];
            oacc[g][dh] = __builtin_amdgcn_mfma_f32_32x32x16_bf16(A.v, vb[h32 * 2 + kc], oacc[g][dh], 0, 0, 0);
          }
      __builtin_amdgcn_s_setprio(0);
    }
    __syncthreads();   // drains next-tile staging; protects buffer reuse
  }

  // ---- epilogue: divide by per-row l, write ----
#pragma unroll
  for (int g = 0; g < 2; g++) {
    float ls = lsum2[g].x + lsum2[g].y;
    float ltot = ls + __shfl_xor(ls, 32);
    if (hi == 0) lsm[w][g][ql] = ltot;
  }
  __syncthreads();
#pragma unroll
  for (int g = 0; g < 2; g++) {
    float rl[16];
#pragma unroll
    for (int r = 0; r < 16; r++)
      rl[r] = 1.0f / lsm[w][g][(r & 3) + 8 * (r >> 2) + 4 * hi];
    size_t obase = tokBase + qt * 256 + w * 64 + g * 32;
#pragma unroll
    for (int dh = 0; dh < 2; dh++)
#pragma unroll
      for (int r = 0; r < 16; r++) {
        int qrw = (r & 3) + 8 * (r >> 2) + 4 * hi;
        O[(obase + qrw) * 1024 + colBase + dh * 32 + ql] = (__bf16)(oacc[g][dh][r] * rl[r]);
      }
  }
}

// ---------------------------------------------------------------------------
extern "C" void kernel_launch(void* const* d_in, const int* in_sizes, int n_in,
                              void* d_out, int out_size, void* d_ws, size_t ws_size,
                              hipStream_t stream)
{
  const float* x         = (const float*)d_in[0];
  const float* rbb_ln_g  = (const float*)d_in[2];
  const float* rbb_ln_b  = (const float*)d_in[3];
  const float* rbb_W     = (const float*)d_in[4];
  const float* rbb_b     = (const float*)d_in[5];
  const float* rba_ln_g  = (const float*)d_in[6];
  const float* rba_ln_b  = (const float*)d_in[7];
  const float* rba_W     = (const float*)d_in[8];
  const float* rba_b     = (const float*)d_in[9];
  const float* attn_ln_g = (const float*)d_in[10];
  const float* attn_ln_b = (const float*)d_in[11];
  const float* Wq = (const float*)d_in[12];
  const float* bq = (const float*)d_in[13];
  const float* Wk = (const float*)d_in[14];
  const float* bk = (const float*)d_in[15];
  const float* Wv = (const float*)d_in[16];
  const float* bv = (const float*)d_in[17];
  const float* Wo = (const float*)d_in[18];
  const float* bo = (const float*)d_in[19];

  char* ws = (char*)d_ws;
  __bf16* X   = (__bf16*)(ws);                    // residual stream, bf16 16.8MB
  __bf16* Tb  = (__bf16*)(ws + 33554432);         // bf16 T (aliases Q region)
  __bf16* Qbf = (__bf16*)(ws + 33554432);
  __bf16* Kbf = (__bf16*)(ws + 33554432 + 16777216);
  __bf16* Abf = (__bf16*)(ws + 67108864);         // LN output
  __bf16* VT  = (__bf16*)(ws + 83886080);         // [4][16][64][2048] bf16
  __bf16* Cbf = (__bf16*)(ws + 100663296);        // attn output
  __bf16* Wbf = (__bf16*)(ws + 117440512);        // 24 weight matrices (48MB)
  auto WT = [&](int m) { return Wbf + (size_t)m * 1048576; };

  float* outF = (float*)d_out;
  dim3 blk(256);

  wt_conv<<<24 * 1024, blk, 0, stream>>>(rbb_W, Wq, Wk, Wv, Wo, rba_W, Wbf);

  // rbb resnet (block 0 residual = f32 input x; block 1 residual = bf16 X)
  ln_relu<0><<<8192, blk, 0, stream>>>(x, rbb_ln_g + 0 * 1024, rbb_ln_b + 0 * 1024, Abf);
  gemm_bt<0, 1><<<512, blk, 0, stream>>>(Abf, WT(0), rbb_b + 0 * 1024, nullptr, nullptr, Tb);
  ln_relu<1><<<8192, blk, 0, stream>>>(Tb, rbb_ln_g + 1 * 1024, rbb_ln_b + 1 * 1024, Abf);
  gemm_bt<1, 1><<<512, blk, 0, stream>>>(Abf, WT(1), rbb_b + 1 * 1024, x, nullptr, X);

  ln_relu<1><<<8192, blk, 0, stream>>>(X, rbb_ln_g + 2 * 1024, rbb_ln_b + 2 * 1024, Abf);
  gemm_bt<0, 1><<<512, blk, 0, stream>>>(Abf, WT(2), rbb_b + 2 * 1024, nullptr, nullptr, Tb);
  ln_relu<1><<<8192, blk, 0, stream>>>(Tb, rbb_ln_g + 3 * 1024, rbb_ln_b + 3 * 1024, Abf);
  gemm_bt<2, 1><<<512, blk, 0, stream>>>(Abf, WT(3), rbb_b + 3 * 1024, X, nullptr, X);

  // attention layers (fused QKV projection)
  for (int l = 0; l < 4; l++) {
    ln_relu<1><<<8192, blk, 0, stream>>>(X, attn_ln_g + l * 1024, attn_ln_b + l * 1024, Abf);
    gemm_qkv<<<1536, blk, 0, stream>>>(Abf, WT(4 + 3 * l),
                                       bq + l * 1024, bk + l * 1024, bv + l * 1024,
                                       Qbf, Kbf, VT);
    attn_fwd<<<512, blk, 0, stream>>>(Qbf, Kbf, VT, Cbf);
    gemm_bt<2, 1><<<512, blk, 0, stream>>>(Cbf, WT(16 + l), bo + l * 1024, X, nullptr, X);
  }

  // rba resnet (last GEMM writes f32 d_out directly)
  for (int i = 0; i < 2; i++) {
    ln_relu<1><<<8192, blk, 0, stream>>>(X, rba_ln_g + (i * 2 + 0) * 1024, rba_ln_b + (i * 2 + 0) * 1024, Abf);
    gemm_bt<0, 1><<<512, blk, 0, stream>>>(Abf, WT(20 + i * 2 + 0), rba_b + (i * 2 + 0) * 1024, nullptr, nullptr, Tb);
    ln_relu<1><<<8192, blk, 0, stream>>>(Tb, rba_ln_g + (i * 2 + 1) * 1024, rba_ln_b + (i * 2 + 1) * 1024, Abf);
    if (i == 0)
      gemm_bt<2, 1><<<512, blk, 0, stream>>>(Abf, WT(21), rba_b + 1 * 1024, X, nullptr, X);
    else
      gemm_bt<2, 0><<<512, blk, 0, stream>>>(Abf, WT(23), rba_b + 3 * 1024, X, outF, nullptr);
  }
}

// Round 15
// 1027.719 us; speedup vs baseline: 1.2040x; 1.0043x over previous
//
#include <hip/hip_runtime.h>

// ---------------------------------------------------------------------------
// Transformer: rbb resnet (2 blocks) -> 4 attention layers -> rba resnet.
// Round 15: attention KVBLK 64 -> 128 (two kh-phases per barrier): per-block
// barrier/vmcnt(0) drains halve 32 -> 16. LDS 65.5KB (still 2 blocks/CU =
// grid cap). Fragment math = R9 formulas + kh offsets; VT swizzle extended
// to 16 groups, g' = (G&8)|((G&7)^(drow&7)). All else = R14 (X bf16, etc).
// ---------------------------------------------------------------------------

typedef __bf16 bf16x8 __attribute__((ext_vector_type(8)));
typedef __bf16 bf16x4 __attribute__((ext_vector_type(4)));
typedef float  f32x4  __attribute__((ext_vector_type(4)));
typedef float  f32x16 __attribute__((ext_vector_type(16)));

#define SCQ 0.18033688011112042f   // log2(e)/8, folded into Q projection

__device__ __forceinline__ void gl_lds16(const void* g, void* l) {
  __builtin_amdgcn_global_load_lds(
      (const __attribute__((address_space(1))) void*)g,
      (__attribute__((address_space(3))) void*)l, 16, 0, 0);
}

// ---------------------------------------------------------------------------
// Weight convert+transpose: W f32 [1024][1024] -> WT bf16 [n][k].
// Order: 0-3 rbb, 4..15 per-layer QKV (Wq|Wk|Wv contiguous), 16-19 Wo,
// 20-23 rba.
// ---------------------------------------------------------------------------
__global__ __launch_bounds__(256) void wt_conv(
    const float* __restrict__ rbbW, const float* __restrict__ Wq,
    const float* __restrict__ Wk,   const float* __restrict__ Wv,
    const float* __restrict__ Wo,   const float* __restrict__ rbaW,
    __bf16* __restrict__ out)
{
  int bid = blockIdx.x;
  int m = bid >> 10;
  int tile = bid & 1023;
  int tr = tile >> 5, tc = tile & 31;
  const float* src;
  if (m < 4)       src = rbbW + (size_t)m * 1048576;
  else if (m < 16) {
    int l = (m - 4) / 3, r = (m - 4) % 3;
    const float* w3 = (r == 0) ? Wq : (r == 1) ? Wk : Wv;
    src = w3 + (size_t)l * 1048576;
  }
  else if (m < 20) src = Wo   + (size_t)(m - 16) * 1048576;
  else             src = rbaW + (size_t)(m - 20) * 1048576;
  __bf16* dst = out + (size_t)m * 1048576;

  __shared__ float tileS[32][33];
  int tx = threadIdx.x & 31, ty = threadIdx.x >> 5;
#pragma unroll
  for (int i = 0; i < 32; i += 8)
    tileS[ty + i][tx] = src[(size_t)(tr * 32 + ty + i) * 1024 + tc * 32 + tx];
  __syncthreads();
#pragma unroll
  for (int i = 0; i < 32; i += 8)
    dst[(size_t)(tc * 32 + ty + i) * 1024 + tr * 32 + tx] = (__bf16)tileS[tx][ty + i];
}

// ---------------------------------------------------------------------------
// LayerNorm + ReLU, [row][1024] -> bf16 [row][1024]. INBF: input dtype.
// ---------------------------------------------------------------------------
template <int INBF>
__global__ __launch_bounds__(256) void ln_relu(
    const void* __restrict__ inv, const float* __restrict__ g,
    const float* __restrict__ bta, __bf16* __restrict__ out)
{
  int row = blockIdx.x;
  int t = threadIdx.x;
  float4 v;
  if constexpr (INBF) {
    bf16x4 b4 = ((const bf16x4*)((const __bf16*)inv + (size_t)row * 1024))[t];
    v = make_float4((float)b4[0], (float)b4[1], (float)b4[2], (float)b4[3]);
  } else {
    v = ((const float4*)((const float*)inv + (size_t)row * 1024))[t];
  }
  float s  = v.x + v.y + v.z + v.w;
  float s2 = v.x * v.x + v.y * v.y + v.z * v.z + v.w * v.w;
#pragma unroll
  for (int o = 32; o > 0; o >>= 1) {
    s  += __shfl_xor(s, o);
    s2 += __shfl_xor(s2, o);
  }
  __shared__ float rs[4], rs2[4];
  int w = t >> 6, lane = t & 63;
  if (lane == 0) { rs[w] = s; rs2[w] = s2; }
  __syncthreads();
  s  = rs[0] + rs[1] + rs[2] + rs[3];
  s2 = rs2[0] + rs2[1] + rs2[2] + rs2[3];
  float mu  = s * (1.0f / 1024.0f);
  float var = s2 * (1.0f / 1024.0f) - mu * mu;
  float ri  = rsqrtf(var + 1e-5f);
  float4 gv = ((const float4*)g)[t];
  float4 bv = ((const float4*)bta)[t];
  float y0 = fmaxf(0.f, (v.x - mu) * ri * gv.x + bv.x);
  float y1 = fmaxf(0.f, (v.y - mu) * ri * gv.y + bv.y);
  float y2 = fmaxf(0.f, (v.z - mu) * ri * gv.z + bv.z);
  float y3 = fmaxf(0.f, (v.w - mu) * ri * gv.w + bv.w);
  bf16x4 o4 = { (__bf16)y0, (__bf16)y1, (__bf16)y2, (__bf16)y3 };
  *(bf16x4*)(out + (size_t)row * 1024 + t * 4) = o4;
}

// ---------------------------------------------------------------------------
// GEMM K-loop BK=64: 128x128 tile, 2-buffer, counted vmcnt(8), raw barriers.
// LDS [row][64] with 16B-group XOR swizzle g^(row&7), source-pre-swizzled.
// ---------------------------------------------------------------------------
#define STAGE8(k0, nb)                                                         \
  {                                                                            \
    const __bf16* Ak = Ag + (k0);                                              \
    const __bf16* Bk = Bg + (k0);                                              \
    char* Ad = (char*)As + (nb) * 16384 + w * 1024;                            \
    char* Bd = (char*)Bs + (nb) * 16384 + w * 1024;                            \
    gl_lds16(Ak,         Ad);                                                  \
    gl_lds16(Ak + 32768, Ad + 4096);                                           \
    gl_lds16(Ak + 65536, Ad + 8192);                                           \
    gl_lds16(Ak + 98304, Ad + 12288);                                          \
    gl_lds16(Bk,         Bd);                                                  \
    gl_lds16(Bk + 32768, Bd + 4096);                                           \
    gl_lds16(Bk + 65536, Bd + 8192);                                           \
    gl_lds16(Bk + 98304, Bd + 12288);                                          \
  }

#define GEMM_KLOOP64(acc)                                                      \
  STAGE8(0, 0)                                                                 \
  for (int t = 0; t < 16; ++t) {                                               \
    __builtin_amdgcn_s_barrier();                                              \
    if (t < 15) {                                                              \
      STAGE8((t + 1) * 64, (t + 1) & 1)                                        \
      asm volatile("s_waitcnt vmcnt(8)" ::: "memory");                         \
    } else {                                                                   \
      asm volatile("s_waitcnt vmcnt(0)" ::: "memory");                         \
    }                                                                          \
    __builtin_amdgcn_s_barrier();                                              \
    const __bf16* Asb = As + (t & 1) * 8192;                                   \
    const __bf16* Bsb = Bs + (t & 1) * 8192;                                   \
    _Pragma("unroll")                                                          \
    for (int kk = 0; kk < 2; kk++) {                                           \
      bf16x8 a[4], b[4];                                                       \
      _Pragma("unroll")                                                        \
      for (int mi = 0; mi < 4; mi++)                                           \
        a[mi] = *(const bf16x8*)&Asb[(wr * 64 + mi * 16 + fr) * 64 +           \
                                     (((kk * 4 + fq) ^ (fr & 7)) * 8)];        \
      _Pragma("unroll")                                                        \
      for (int ni = 0; ni < 4; ni++)                                           \
        b[ni] = *(const bf16x8*)&Bsb[(wc * 64 + ni * 16 + fr) * 64 +           \
                                     (((kk * 4 + fq) ^ (fr & 7)) * 8)];        \
      _Pragma("unroll")                                                        \
      for (int mi = 0; mi < 4; mi++)                                           \
        _Pragma("unroll")                                                      \
        for (int ni = 0; ni < 4; ni++)                                         \
          acc[mi][ni] = __builtin_amdgcn_mfma_f32_16x16x32_bf16(               \
              a[mi], b[ni], acc[mi][ni], 0, 0, 0);                             \
    }                                                                          \
  }

// ---------------------------------------------------------------------------
// GEMM: out[M=8192][1024] = A(bf16) @ W + bias (+ res). BT = W^T bf16 [n][k].
// RESID: 0 = none, 1 = f32 residual, 2 = bf16 residual.
// OUTMODE: 0 = f32 row-major, 1 = bf16 row-major.
// ---------------------------------------------------------------------------
template <int RESID, int OUTMODE>
__global__ __launch_bounds__(256) void gemm_bt(
    const __bf16* __restrict__ A, const __bf16* __restrict__ BT,
    const float* __restrict__ bias, const void* __restrict__ resv,
    float* __restrict__ outF, __bf16* __restrict__ outB)
{
  __shared__ __bf16 As[2 * 128 * 64];
  __shared__ __bf16 Bs[2 * 128 * 64];
  int t0 = threadIdx.x;
  int lane = t0 & 63, w = t0 >> 6;
  int wr = w >> 1, wc = w & 1;
  int fr = lane & 15, fq = lane >> 4;
  int orig = blockIdx.x;
  int bid = (orig & 7) * 64 + (orig >> 3);  // XCD-chunked, 512 % 8 == 0
  int bm = bid >> 3, bn = bid & 7;

  f32x4 acc[4][4] = {};

  int srow = t0 >> 3, sg = t0 & 7;
  int sgx = sg ^ (srow & 7);
  const __bf16* Ag = A  + (size_t)(bm * 128 + srow) * 1024 + sgx * 8;
  const __bf16* Bg = BT + (size_t)(bn * 128 + srow) * 1024 + sgx * 8;

  GEMM_KLOOP64(acc)

#pragma unroll
  for (int ni = 0; ni < 4; ni++) {
    int col = bn * 128 + wc * 64 + ni * 16 + fr;
    float bcol = bias[col];
#pragma unroll
    for (int mi = 0; mi < 4; mi++) {
      int row0 = bm * 128 + wr * 64 + mi * 16 + fq * 4;
#pragma unroll
      for (int r = 0; r < 4; r++) {
        size_t idx = (size_t)(row0 + r) * 1024 + col;
        float v = acc[mi][ni][r] + bcol;
        if constexpr (RESID == 1) v += ((const float*)resv)[idx];
        if constexpr (RESID == 2) v += (float)((const __bf16*)resv)[idx];
        if constexpr (OUTMODE == 1) outB[idx] = (__bf16)v;
        else                        outF[idx] = v;
      }
    }
  }
}

// ---------------------------------------------------------------------------
// Fused QKV GEMM (R9 version): A[8192][1024] @ WTqkv^T (N=3072). bn 0-7 -> Q
// (pre-scaled by SCQ), 8-15 -> K, 16-23 -> V (VT[b][h][dd][s]).
// ---------------------------------------------------------------------------
__global__ __launch_bounds__(256) void gemm_qkv(
    const __bf16* __restrict__ A, const __bf16* __restrict__ BT,
    const float* __restrict__ bq, const float* __restrict__ bk,
    const float* __restrict__ bv,
    __bf16* __restrict__ Qo, __bf16* __restrict__ Ko, __bf16* __restrict__ VTo)
{
  __shared__ __bf16 As[2 * 128 * 64];
  __shared__ __bf16 Bs[2 * 128 * 64];
  int t0 = threadIdx.x;
  int lane = t0 & 63, w = t0 >> 6;
  int wr = w >> 1, wc = w & 1;
  int fr = lane & 15, fq = lane >> 4;
  int orig = blockIdx.x;
  int bid = (orig & 7) * 192 + (orig >> 3);  // 1536 % 8 == 0
  int bm = bid / 24, bn = bid % 24;

  f32x4 acc[4][4] = {};

  int srow = t0 >> 3, sg = t0 & 7;
  int sgx = sg ^ (srow & 7);
  const __bf16* Ag = A  + (size_t)(bm * 128 + srow) * 1024 + sgx * 8;
  const __bf16* Bg = BT + (size_t)(bn * 128 + srow) * 1024 + sgx * 8;

  GEMM_KLOOP64(acc)

#pragma unroll
  for (int ni = 0; ni < 4; ni++) {
    int col3 = bn * 128 + wc * 64 + ni * 16 + fr;
#pragma unroll
    for (int mi = 0; mi < 4; mi++) {
      int row0 = bm * 128 + wr * 64 + mi * 16 + fq * 4;
      if (bn < 8) {               // Q, pre-scaled
        float bcol = bq[col3];
#pragma unroll
        for (int r = 0; r < 4; r++)
          Qo[(size_t)(row0 + r) * 1024 + col3] = (__bf16)((acc[mi][ni][r] + bcol) * SCQ);
      } else if (bn < 16) {       // K
        int c = col3 - 1024;
        float bcol = bk[c];
#pragma unroll
        for (int r = 0; r < 4; r++)
          Ko[(size_t)(row0 + r) * 1024 + c] = (__bf16)(acc[mi][ni][r] + bcol);
      } else {                    // V -> VT[b][h][dd][s], rows are s-contig
        int c = col3 - 2048;
        float bcol = bv[c];
        int b_ = row0 >> 11, s0 = row0 & 2047;
        size_t idx = ((size_t)((b_ * 16 + (c >> 6)) * 64 + (c & 63))) * 2048 + s0;
        bf16x4 o4;
#pragma unroll
        for (int r = 0; r < 4; r++) o4[r] = (__bf16)(acc[mi][ni][r] + bcol);
        *(bf16x4*)&VTo[idx] = o4;
      }
    }
  }
}

// ---------------------------------------------------------------------------
// Flash attention, KVBLK=128 (two kh-phases per barrier). Swapped-QK^T 32x32,
// 2 q-groups/wave, grid = 64 bh * 8 qtiles = 512 blocks, 4 waves.
// Ks [2][128 kj][64 d]; VTs [2][64 d][128 kj] (16 groups/row, swizzle
// g' = (G&8)|((G&7)^(drow&7))). 16 barriers/block instead of 32.
// Q arrives pre-scaled by log2(e)/8 -> exp2(s) directly, no max-sub.
// ---------------------------------------------------------------------------
__global__ __launch_bounds__(256, 2) void attn_fwd(
    const __bf16* __restrict__ Q, const __bf16* __restrict__ K,
    const __bf16* __restrict__ VT, __bf16* __restrict__ O)
{
  int orig = blockIdx.x;
  int bid = (orig & 7) * 64 + (orig >> 3);   // XCD-bijective: 512 % 8 == 0
  int bh = bid >> 3, qt = bid & 7;
  int h = bh & 15, b = bh >> 4;
  int t = threadIdx.x, lane = t & 63, w = t >> 6;
  int ql = lane & 31, hi = lane >> 5;
  size_t tokBase = (size_t)b * 2048;
  int colBase = h * 64;

  __shared__ __bf16 Ks[2 * 128 * 64];   // dbuf [kj][64d], src-XOR-swizzled
  __shared__ __bf16 VTs[2 * 64 * 128];  // dbuf [d][128kj], src-XOR-swizzled
  __shared__ float  lsm[4][2][32];

  // Q fragments: group g, lane holds Q[q = qt*256 + w*64 + g*32 + ql][d=c*16+hi*8+i]
  bf16x8 qf[2][4];
#pragma unroll
  for (int g = 0; g < 2; g++) {
    const __bf16* qrow = Q + (tokBase + qt * 256 + w * 64 + g * 32 + ql) * 1024 + colBase + hi * 8;
#pragma unroll
    for (int c = 0; c < 4; c++) qf[g][c] = *(const bf16x8*)(qrow + c * 16);
  }

  f32x16 oacc[2][2] = {};
  float2 lsum2[2] = {};

  // K staging: wave w stages rows w*8 + j*32 + (lane>>3), j=0..3
  int srowK = w * 8 + (lane >> 3);
  int sgcK  = (lane & 7) ^ (lane >> 3);
  const __bf16* kSrc = K + (tokBase + srowK) * 1024 + colBase + sgcK * 8;
  char* kDst = (char*)Ks + w * 1024;
  // VT staging: wave w stages d-rows w*4 + jj*16 + (lane>>4), jj=0..3;
  // 16 groups/row; source group = (g&8)|((g&7)^(row&7)) (row&7 jj-invariant)
  int srowV = w * 4 + (lane >> 4);
  int gV = lane & 15;
  int sgcV = (gV & 8) | ((gV & 7) ^ (srowV & 7));
  const __bf16* vtSrc = VT + ((size_t)bh * 64 + srowV) * 2048 + sgcV * 8;
  char* vtDst = (char*)VTs + w * 1024;

#define ASTG(nb)                                                               \
  {                                                                            \
    _Pragma("unroll")                                                          \
    for (int j = 0; j < 4; j++) {                                              \
      gl_lds16(kSrc + j * 32768,  kDst + (nb) * 16384 + j * 4096);             \
      gl_lds16(vtSrc + j * 32768, vtDst + (nb) * 16384 + j * 4096);            \
    }                                                                          \
  }

  // prologue: stage tile 0 into buf 0
  ASTG(0)
  kSrc += 131072; vtSrc += 128;
  __syncthreads();

  for (int kt = 0; kt < 16; ++kt) {
    if (kt + 1 < 16) {           // stage next 128-kj tile into other buffer
      ASTG((kt + 1) & 1)
      kSrc += 131072; vtSrc += 128;
    }
    const __bf16* Ksb  = Ks  + (kt & 1) * 8192;
    const __bf16* VTsb = VTs + (kt & 1) * 8192;

#pragma unroll
    for (int kh = 0; kh < 2; kh++) {
      // ---- S^T = K.Q^T: kf reads shared by both q-groups ----
      f32x16 s_[2][2] = {};
      __builtin_amdgcn_s_setprio(1);
#pragma unroll
      for (int c = 0; c < 4; c++) {
        int g2 = c * 2 + hi;
        bf16x8 kf0 = *(const bf16x8*)&Ksb[(kh * 64 + ql) * 64 + ((g2 ^ (ql & 7)) * 8)];
        bf16x8 kf1 = *(const bf16x8*)&Ksb[(kh * 64 + 32 + ql) * 64 + ((g2 ^ (ql & 7)) * 8)];
#pragma unroll
        for (int g = 0; g < 2; g++) {
          s_[g][0] = __builtin_amdgcn_mfma_f32_32x32x16_bf16(kf0, qf[g][c], s_[g][0], 0, 0, 0);
          s_[g][1] = __builtin_amdgcn_mfma_f32_32x32x16_bf16(kf1, qf[g][c], s_[g][1], 0, 0, 0);
        }
      }
      __builtin_amdgcn_s_setprio(0);

      // ---- softmax per group (Q pre-scaled, no max-sub) -> P A-fragments ----
      unsigned int pa[2][2][2][4];
#pragma unroll
      for (int g = 0; g < 2; g++) {
#pragma unroll
        for (int h32 = 0; h32 < 2; h32++) {
          float p[16];
#pragma unroll
          for (int r = 0; r < 16; r++)
            p[r] = __builtin_amdgcn_exp2f(s_[g][h32][r]);
#pragma unroll
          for (int i = 0; i < 8; i++) {
            lsum2[g].x += p[2 * i];
            lsum2[g].y += p[2 * i + 1];
          }
          unsigned int cw[8];
#pragma unroll
          for (int i = 0; i < 8; i++) {
            unsigned int d_;
            asm("v_cvt_pk_bf16_f32 %0, %1, %2" : "=v"(d_) : "v"(p[2 * i]), "v"(p[2 * i + 1]));
            cw[i] = d_;
          }
          asm("v_permlane32_swap_b32 %0, %1" : "+v"(cw[2]), "+v"(cw[0]));
          asm("v_permlane32_swap_b32 %0, %1" : "+v"(cw[3]), "+v"(cw[1]));
          asm("v_permlane32_swap_b32 %0, %1" : "+v"(cw[6]), "+v"(cw[4]));
          asm("v_permlane32_swap_b32 %0, %1" : "+v"(cw[7]), "+v"(cw[5]));
          pa[g][h32][0][0] = cw[0]; pa[g][h32][0][1] = cw[1];
          pa[g][h32][0][2] = cw[2]; pa[g][h32][0][3] = cw[3];
          pa[g][h32][1][0] = cw[4]; pa[g][h32][1][1] = cw[5];
          pa[g][h32][1][2] = cw[6]; pa[g][h32][1][3] = cw[7];
        }
      }

      // ---- PV: vb reads shared by both q-groups ----
#pragma unroll
      for (int dh = 0; dh < 2; dh++) {
        int drow = dh * 32 + ql;
        int dsw = drow & 7;
        bf16x8 vb[4];
#pragma unroll
        for (int h32 = 0; h32 < 2; h32++)
#pragma unroll
          for (int kc = 0; kc < 2; kc++) {
            int g2 = h32 * 4 + kc * 2 + hi;  // kj group within kh-half
            vb[h32 * 2 + kc] = *(const bf16x8*)&VTsb[drow * 128 + ((kh * 8 + (g2 ^ dsw)) * 8)];
          }
        __builtin_amdgcn_s_setprio(1);
#pragma unroll
        for (int g = 0; g < 2; g++)
#pragma unroll
          for (int h32 = 0; h32 < 2; h32++)
#pragma unroll
            for (int kc = 0; kc < 2; kc++) {
              union { unsigned int u[4]; bf16x8 v; } A;
              A.u[0] = pa[g][h32][kc][0]; A.u[1] = pa[g][h32][kc][1];
              A.u[2] = pa[g][h32][kc][2]; A.u[3] = pa[g][h32][kc][3];
              oacc[g][dh] = __builtin_amdgcn_mfma_f32_32x32x16_bf16(A.v, vb[h32 * 2 + kc], oacc[g][dh], 0, 0, 0);
            }
        __builtin_amdgcn_s_setprio(0);
      }
    }
    __syncthreads();   // drains next-tile staging; protects buffer reuse
  }
#undef ASTG

  // ---- epilogue: divide by per-row l, write ----
#pragma unroll
  for (int g = 0; g < 2; g++) {
    float ls = lsum2[g].x + lsum2[g].y;
    float ltot = ls + __shfl_xor(ls, 32);
    if (hi == 0) lsm[w][g][ql] = ltot;
  }
  __syncthreads();
#pragma unroll
  for (int g = 0; g < 2; g++) {
    float rl[16];
#pragma unroll
    for (int r = 0; r < 16; r++)
      rl[r] = 1.0f / lsm[w][g][(r & 3) + 8 * (r >> 2) + 4 * hi];
    size_t obase = tokBase + qt * 256 + w * 64 + g * 32;
#pragma unroll
    for (int dh = 0; dh < 2; dh++)
#pragma unroll
      for (int r = 0; r < 16; r++) {
        int qrw = (r & 3) + 8 * (r >> 2) + 4 * hi;
        O[(obase + qrw) * 1024 + colBase + dh * 32 + ql] = (__bf16)(oacc[g][dh][r] * rl[r]);
      }
  }
}

// ---------------------------------------------------------------------------
extern "C" void kernel_launch(void* const* d_in, const int* in_sizes, int n_in,
                              void* d_out, int out_size, void* d_ws, size_t ws_size,
                              hipStream_t stream)
{
  const float* x         = (const float*)d_in[0];
  const float* rbb_ln_g  = (const float*)d_in[2];
  const float* rbb_ln_b  = (const float*)d_in[3];
  const float* rbb_W     = (const float*)d_in[4];
  const float* rbb_b     = (const float*)d_in[5];
  const float* rba_ln_g  = (const float*)d_in[6];
  const float* rba_ln_b  = (const float*)d_in[7];
  const float* rba_W     = (const float*)d_in[8];
  const float* rba_b     = (const float*)d_in[9];
  const float* attn_ln_g = (const float*)d_in[10];
  const float* attn_ln_b = (const float*)d_in[11];
  const float* Wq = (const float*)d_in[12];
  const float* bq = (const float*)d_in[13];
  const float* Wk = (const float*)d_in[14];
  const float* bk = (const float*)d_in[15];
  const float* Wv = (const float*)d_in[16];
  const float* bv = (const float*)d_in[17];
  const float* Wo = (const float*)d_in[18];
  const float* bo = (const float*)d_in[19];

  char* ws = (char*)d_ws;
  __bf16* X   = (__bf16*)(ws);                    // residual stream, bf16 16.8MB
  __bf16* Tb  = (__bf16*)(ws + 33554432);         // bf16 T (aliases Q region)
  __bf16* Qbf = (__bf16*)(ws + 33554432);
  __bf16* Kbf = (__bf16*)(ws + 33554432 + 16777216);
  __bf16* Abf = (__bf16*)(ws + 67108864);         // LN output
  __bf16* VT  = (__bf16*)(ws + 83886080);         // [4][16][64][2048] bf16
  __bf16* Cbf = (__bf16*)(ws + 100663296);        // attn output
  __bf16* Wbf = (__bf16*)(ws + 117440512);        // 24 weight matrices (48MB)
  auto WT = [&](int m) { return Wbf + (size_t)m * 1048576; };

  float* outF = (float*)d_out;
  dim3 blk(256);

  wt_conv<<<24 * 1024, blk, 0, stream>>>(rbb_W, Wq, Wk, Wv, Wo, rba_W, Wbf);

  // rbb resnet (block 0 residual = f32 input x; block 1 residual = bf16 X)
  ln_relu<0><<<8192, blk, 0, stream>>>(x, rbb_ln_g + 0 * 1024, rbb_ln_b + 0 * 1024, Abf);
  gemm_bt<0, 1><<<512, blk, 0, stream>>>(Abf, WT(0), rbb_b + 0 * 1024, nullptr, nullptr, Tb);
  ln_relu<1><<<8192, blk, 0, stream>>>(Tb, rbb_ln_g + 1 * 1024, rbb_ln_b + 1 * 1024, Abf);
  gemm_bt<1, 1><<<512, blk, 0, stream>>>(Abf, WT(1), rbb_b + 1 * 1024, x, nullptr, X);

  ln_relu<1><<<8192, blk, 0, stream>>>(X, rbb_ln_g + 2 * 1024, rbb_ln_b + 2 * 1024, Abf);
  gemm_bt<0, 1><<<512, blk, 0, stream>>>(Abf, WT(2), rbb_b + 2 * 1024, nullptr, nullptr, Tb);
  ln_relu<1><<<8192, blk, 0, stream>>>(Tb, rbb_ln_g + 3 * 1024, rbb_ln_b + 3 * 1024, Abf);
  gemm_bt<2, 1><<<512, blk, 0, stream>>>(Abf, WT(3), rbb_b + 3 * 1024, X, nullptr, X);

  // attention layers (fused QKV projection)
  for (int l = 0; l < 4; l++) {
    ln_relu<1><<<8192, blk, 0, stream>>>(X, attn_ln_g + l * 1024, attn_ln_b + l * 1024, Abf);
    gemm_qkv<<<1536, blk, 0, stream>>>(Abf, WT(4 + 3 * l),
                                       bq + l * 1024, bk + l * 1024, bv + l * 1024,
                                       Qbf, Kbf, VT);
    attn_fwd<<<512, blk, 0, stream>>>(Qbf, Kbf, VT, Cbf);
    gemm_bt<2, 1><<<512, blk, 0, stream>>>(Cbf, WT(16 + l), bo + l * 1024, X, nullptr, X);
  }

  // rba resnet (last GEMM writes f32 d_out directly)
  for (int i = 0; i < 2; i++) {
    ln_relu<1><<<8192, blk, 0, stream>>>(X, rba_ln_g + (i * 2 + 0) * 1024, rba_ln_b + (i * 2 + 0) * 1024, Abf);
    gemm_bt<0, 1><<<512, blk, 0, stream>>>(Abf, WT(20 + i * 2 + 0), rba_b + (i * 2 + 0) * 1024, nullptr, nullptr, Tb);
    ln_relu<1><<<8192, blk, 0, stream>>>(Tb, rba_ln_g + (i * 2 + 1) * 1024, rba_ln_b + (i * 2 + 1) * 1024, Abf);
    if (i == 0)
      gemm_bt<2, 1><<<512, blk, 0, stream>>>(Abf, WT(21), rba_b + 1 * 1024, X, nullptr, X);
    else
      gemm_bt<2, 0><<<512, blk, 0, stream>>>(Abf, WT(23), rba_b + 3 * 1024, X, outF, nullptr);
  }
}

// Round 16
// 1027.633 us; speedup vs baseline: 1.2041x; 1.0001x over previous
//
#include <hip/hip_runtime.h>

// ---------------------------------------------------------------------------
// Transformer: rbb resnet (2 blocks) -> 4 attention layers -> rba resnet.
// Round 15: attention KVBLK 64 -> 128 (two kh-phases per barrier): per-block
// barrier/vmcnt(0) drains halve 32 -> 16. LDS 65.5KB (still 2 blocks/CU =
// grid cap). Fragment math = R9 formulas + kh offsets; VT swizzle extended
// to 16 groups, g' = (G&8)|((G&7)^(drow&7)). All else = R14 (X bf16, etc).
// ---------------------------------------------------------------------------

typedef __bf16 bf16x8 __attribute__((ext_vector_type(8)));
typedef __bf16 bf16x4 __attribute__((ext_vector_type(4)));
typedef float  f32x4  __attribute__((ext_vector_type(4)));
typedef float  f32x16 __attribute__((ext_vector_type(16)));

#define SCQ 0.18033688011112042f   // log2(e)/8, folded into Q projection

__device__ __forceinline__ void gl_lds16(const void* g, void* l) {
  __builtin_amdgcn_global_load_lds(
      (const __attribute__((address_space(1))) void*)g,
      (__attribute__((address_space(3))) void*)l, 16, 0, 0);
}

// ---------------------------------------------------------------------------
// Weight convert+transpose: W f32 [1024][1024] -> WT bf16 [n][k].
// Order: 0-3 rbb, 4..15 per-layer QKV (Wq|Wk|Wv contiguous), 16-19 Wo,
// 20-23 rba.
// ---------------------------------------------------------------------------
__global__ __launch_bounds__(256) void wt_conv(
    const float* __restrict__ rbbW, const float* __restrict__ Wq,
    const float* __restrict__ Wk,   const float* __restrict__ Wv,
    const float* __restrict__ Wo,   const float* __restrict__ rbaW,
    __bf16* __restrict__ out)
{
  int bid = blockIdx.x;
  int m = bid >> 10;
  int tile = bid & 1023;
  int tr = tile >> 5, tc = tile & 31;
  const float* src;
  if (m < 4)       src = rbbW + (size_t)m * 1048576;
  else if (m < 16) {
    int l = (m - 4) / 3, r = (m - 4) % 3;
    const float* w3 = (r == 0) ? Wq : (r == 1) ? Wk : Wv;
    src = w3 + (size_t)l * 1048576;
  }
  else if (m < 20) src = Wo   + (size_t)(m - 16) * 1048576;
  else             src = rbaW + (size_t)(m - 20) * 1048576;
  __bf16* dst = out + (size_t)m * 1048576;

  __shared__ float tileS[32][33];
  int tx = threadIdx.x & 31, ty = threadIdx.x >> 5;
#pragma unroll
  for (int i = 0; i < 32; i += 8)
    tileS[ty + i][tx] = src[(size_t)(tr * 32 + ty + i) * 1024 + tc * 32 + tx];
  __syncthreads();
#pragma unroll
  for (int i = 0; i < 32; i += 8)
    dst[(size_t)(tc * 32 + ty + i) * 1024 + tr * 32 + tx] = (__bf16)tileS[tx][ty + i];
}

// ---------------------------------------------------------------------------
// LayerNorm + ReLU, [row][1024] -> bf16 [row][1024]. INBF: input dtype.
// ---------------------------------------------------------------------------
template <int INBF>
__global__ __launch_bounds__(256) void ln_relu(
    const void* __restrict__ inv, const float* __restrict__ g,
    const float* __restrict__ bta, __bf16* __restrict__ out)
{
  int row = blockIdx.x;
  int t = threadIdx.x;
  float4 v;
  if constexpr (INBF) {
    bf16x4 b4 = ((const bf16x4*)((const __bf16*)inv + (size_t)row * 1024))[t];
    v = make_float4((float)b4[0], (float)b4[1], (float)b4[2], (float)b4[3]);
  } else {
    v = ((const float4*)((const float*)inv + (size_t)row * 1024))[t];
  }
  float s  = v.x + v.y + v.z + v.w;
  float s2 = v.x * v.x + v.y * v.y + v.z * v.z + v.w * v.w;
#pragma unroll
  for (int o = 32; o > 0; o >>= 1) {
    s  += __shfl_xor(s, o);
    s2 += __shfl_xor(s2, o);
  }
  __shared__ float rs[4], rs2[4];
  int w = t >> 6, lane = t & 63;
  if (lane == 0) { rs[w] = s; rs2[w] = s2; }
  __syncthreads();
  s  = rs[0] + rs[1] + rs[2] + rs[3];
  s2 = rs2[0] + rs2[1] + rs2[2] + rs2[3];
  float mu  = s * (1.0f / 1024.0f);
  float var = s2 * (1.0f / 1024.0f) - mu * mu;
  float ri  = rsqrtf(var + 1e-5f);
  float4 gv = ((const float4*)g)[t];
  float4 bv = ((const float4*)bta)[t];
  float y0 = fmaxf(0.f, (v.x - mu) * ri * gv.x + bv.x);
  float y1 = fmaxf(0.f, (v.y - mu) * ri * gv.y + bv.y);
  float y2 = fmaxf(0.f, (v.z - mu) * ri * gv.z + bv.z);
  float y3 = fmaxf(0.f, (v.w - mu) * ri * gv.w + bv.w);
  bf16x4 o4 = { (__bf16)y0, (__bf16)y1, (__bf16)y2, (__bf16)y3 };
  *(bf16x4*)(out + (size_t)row * 1024 + t * 4) = o4;
}

// ---------------------------------------------------------------------------
// GEMM K-loop BK=64: 128x128 tile, 2-buffer, counted vmcnt(8), raw barriers.
// LDS [row][64] with 16B-group XOR swizzle g^(row&7), source-pre-swizzled.
// ---------------------------------------------------------------------------
#define STAGE8(k0, nb)                                                         \
  {                                                                            \
    const __bf16* Ak = Ag + (k0);                                              \
    const __bf16* Bk = Bg + (k0);                                              \
    char* Ad = (char*)As + (nb) * 16384 + w * 1024;                            \
    char* Bd = (char*)Bs + (nb) * 16384 + w * 1024;                            \
    gl_lds16(Ak,         Ad);                                                  \
    gl_lds16(Ak + 32768, Ad + 4096);                                           \
    gl_lds16(Ak + 65536, Ad + 8192);                                           \
    gl_lds16(Ak + 98304, Ad + 12288);                                          \
    gl_lds16(Bk,         Bd);                                                  \
    gl_lds16(Bk + 32768, Bd + 4096);                                           \
    gl_lds16(Bk + 65536, Bd + 8192);                                           \
    gl_lds16(Bk + 98304, Bd + 12288);                                          \
  }

#define GEMM_KLOOP64(acc)                                                      \
  STAGE8(0, 0)                                                                 \
  for (int t = 0; t < 16; ++t) {                                               \
    __builtin_amdgcn_s_barrier();                                              \
    if (t < 15) {                                                              \
      STAGE8((t + 1) * 64, (t + 1) & 1)                                        \
      asm volatile("s_waitcnt vmcnt(8)" ::: "memory");                         \
    } else {                                                                   \
      asm volatile("s_waitcnt vmcnt(0)" ::: "memory");                         \
    }                                                                          \
    __builtin_amdgcn_s_barrier();                                              \
    const __bf16* Asb = As + (t & 1) * 8192;                                   \
    const __bf16* Bsb = Bs + (t & 1) * 8192;                                   \
    _Pragma("unroll")                                                          \
    for (int kk = 0; kk < 2; kk++) {                                           \
      bf16x8 a[4], b[4];                                                       \
      _Pragma("unroll")                                                        \
      for (int mi = 0; mi < 4; mi++)                                           \
        a[mi] = *(const bf16x8*)&Asb[(wr * 64 + mi * 16 + fr) * 64 +           \
                                     (((kk * 4 + fq) ^ (fr & 7)) * 8)];        \
      _Pragma("unroll")                                                        \
      for (int ni = 0; ni < 4; ni++)                                           \
        b[ni] = *(const bf16x8*)&Bsb[(wc * 64 + ni * 16 + fr) * 64 +           \
                                     (((kk * 4 + fq) ^ (fr & 7)) * 8)];        \
      _Pragma("unroll")                                                        \
      for (int mi = 0; mi < 4; mi++)                                           \
        _Pragma("unroll")                                                      \
        for (int ni = 0; ni < 4; ni++)                                         \
          acc[mi][ni] = __builtin_amdgcn_mfma_f32_16x16x32_bf16(               \
              a[mi], b[ni], acc[mi][ni], 0, 0, 0);                             \
    }                                                                          \
  }

// ---------------------------------------------------------------------------
// GEMM: out[M=8192][1024] = A(bf16) @ W + bias (+ res). BT = W^T bf16 [n][k].
// RESID: 0 = none, 1 = f32 residual, 2 = bf16 residual.
// OUTMODE: 0 = f32 row-major, 1 = bf16 row-major.
// ---------------------------------------------------------------------------
template <int RESID, int OUTMODE>
__global__ __launch_bounds__(256) void gemm_bt(
    const __bf16* __restrict__ A, const __bf16* __restrict__ BT,
    const float* __restrict__ bias, const void* __restrict__ resv,
    float* __restrict__ outF, __bf16* __restrict__ outB)
{
  __shared__ __bf16 As[2 * 128 * 64];
  __shared__ __bf16 Bs[2 * 128 * 64];
  int t0 = threadIdx.x;
  int lane = t0 & 63, w = t0 >> 6;
  int wr = w >> 1, wc = w & 1;
  int fr = lane & 15, fq = lane >> 4;
  int orig = blockIdx.x;
  int bid = (orig & 7) * 64 + (orig >> 3);  // XCD-chunked, 512 % 8 == 0
  int bm = bid >> 3, bn = bid & 7;

  f32x4 acc[4][4] = {};

  int srow = t0 >> 3, sg = t0 & 7;
  int sgx = sg ^ (srow & 7);
  const __bf16* Ag = A  + (size_t)(bm * 128 + srow) * 1024 + sgx * 8;
  const __bf16* Bg = BT + (size_t)(bn * 128 + srow) * 1024 + sgx * 8;

  GEMM_KLOOP64(acc)

#pragma unroll
  for (int ni = 0; ni < 4; ni++) {
    int col = bn * 128 + wc * 64 + ni * 16 + fr;
    float bcol = bias[col];
#pragma unroll
    for (int mi = 0; mi < 4; mi++) {
      int row0 = bm * 128 + wr * 64 + mi * 16 + fq * 4;
#pragma unroll
      for (int r = 0; r < 4; r++) {
        size_t idx = (size_t)(row0 + r) * 1024 + col;
        float v = acc[mi][ni][r] + bcol;
        if constexpr (RESID == 1) v += ((const float*)resv)[idx];
        if constexpr (RESID == 2) v += (float)((const __bf16*)resv)[idx];
        if constexpr (OUTMODE == 1) outB[idx] = (__bf16)v;
        else                        outF[idx] = v;
      }
    }
  }
}

// ---------------------------------------------------------------------------
// Fused QKV GEMM (R9 version): A[8192][1024] @ WTqkv^T (N=3072). bn 0-7 -> Q
// (pre-scaled by SCQ), 8-15 -> K, 16-23 -> V (VT[b][h][dd][s]).
// ---------------------------------------------------------------------------
__global__ __launch_bounds__(256) void gemm_qkv(
    const __bf16* __restrict__ A, const __bf16* __restrict__ BT,
    const float* __restrict__ bq, const float* __restrict__ bk,
    const float* __restrict__ bv,
    __bf16* __restrict__ Qo, __bf16* __restrict__ Ko, __bf16* __restrict__ VTo)
{
  __shared__ __bf16 As[2 * 128 * 64];
  __shared__ __bf16 Bs[2 * 128 * 64];
  int t0 = threadIdx.x;
  int lane = t0 & 63, w = t0 >> 6;
  int wr = w >> 1, wc = w & 1;
  int fr = lane & 15, fq = lane >> 4;
  int orig = blockIdx.x;
  int bid = (orig & 7) * 192 + (orig >> 3);  // 1536 % 8 == 0
  int bm = bid / 24, bn = bid % 24;

  f32x4 acc[4][4] = {};

  int srow = t0 >> 3, sg = t0 & 7;
  int sgx = sg ^ (srow & 7);
  const __bf16* Ag = A  + (size_t)(bm * 128 + srow) * 1024 + sgx * 8;
  const __bf16* Bg = BT + (size_t)(bn * 128 + srow) * 1024 + sgx * 8;

  GEMM_KLOOP64(acc)

#pragma unroll
  for (int ni = 0; ni < 4; ni++) {
    int col3 = bn * 128 + wc * 64 + ni * 16 + fr;
#pragma unroll
    for (int mi = 0; mi < 4; mi++) {
      int row0 = bm * 128 + wr * 64 + mi * 16 + fq * 4;
      if (bn < 8) {               // Q, pre-scaled
        float bcol = bq[col3];
#pragma unroll
        for (int r = 0; r < 4; r++)
          Qo[(size_t)(row0 + r) * 1024 + col3] = (__bf16)((acc[mi][ni][r] + bcol) * SCQ);
      } else if (bn < 16) {       // K
        int c = col3 - 1024;
        float bcol = bk[c];
#pragma unroll
        for (int r = 0; r < 4; r++)
          Ko[(size_t)(row0 + r) * 1024 + c] = (__bf16)(acc[mi][ni][r] + bcol);
      } else {                    // V -> VT[b][h][dd][s], rows are s-contig
        int c = col3 - 2048;
        float bcol = bv[c];
        int b_ = row0 >> 11, s0 = row0 & 2047;
        size_t idx = ((size_t)((b_ * 16 + (c >> 6)) * 64 + (c & 63))) * 2048 + s0;
        bf16x4 o4;
#pragma unroll
        for (int r = 0; r < 4; r++) o4[r] = (__bf16)(acc[mi][ni][r] + bcol);
        *(bf16x4*)&VTo[idx] = o4;
      }
    }
  }
}

// ---------------------------------------------------------------------------
// Flash attention, KVBLK=128 (two kh-phases per barrier). Swapped-QK^T 32x32,
// 2 q-groups/wave, grid = 64 bh * 8 qtiles = 512 blocks, 4 waves.
// Ks [2][128 kj][64 d]; VTs [2][64 d][128 kj] (16 groups/row, swizzle
// g' = (G&8)|((G&7)^(drow&7))). 16 barriers/block instead of 32.
// Q arrives pre-scaled by log2(e)/8 -> exp2(s) directly, no max-sub.
// ---------------------------------------------------------------------------
__global__ __launch_bounds__(256, 2) void attn_fwd(
    const __bf16* __restrict__ Q, const __bf16* __restrict__ K,
    const __bf16* __restrict__ VT, __bf16* __restrict__ O)
{
  int orig = blockIdx.x;
  int bid = (orig & 7) * 64 + (orig >> 3);   // XCD-bijective: 512 % 8 == 0
  int bh = bid >> 3, qt = bid & 7;
  int h = bh & 15, b = bh >> 4;
  int t = threadIdx.x, lane = t & 63, w = t >> 6;
  int ql = lane & 31, hi = lane >> 5;
  size_t tokBase = (size_t)b * 2048;
  int colBase = h * 64;

  __shared__ __bf16 Ks[2 * 128 * 64];   // dbuf [kj][64d], src-XOR-swizzled
  __shared__ __bf16 VTs[2 * 64 * 128];  // dbuf [d][128kj], src-XOR-swizzled
  __shared__ float  lsm[4][2][32];

  // Q fragments: group g, lane holds Q[q = qt*256 + w*64 + g*32 + ql][d=c*16+hi*8+i]
  bf16x8 qf[2][4];
#pragma unroll
  for (int g = 0; g < 2; g++) {
    const __bf16* qrow = Q + (tokBase + qt * 256 + w * 64 + g * 32 + ql) * 1024 + colBase + hi * 8;
#pragma unroll
    for (int c = 0; c < 4; c++) qf[g][c] = *(const bf16x8*)(qrow + c * 16);
  }

  f32x16 oacc[2][2] = {};
  float2 lsum2[2] = {};

  // K staging: wave w stages rows w*8 + j*32 + (lane>>3), j=0..3
  int srowK = w * 8 + (lane >> 3);
  int sgcK  = (lane & 7) ^ (lane >> 3);
  const __bf16* kSrc = K + (tokBase + srowK) * 1024 + colBase + sgcK * 8;
  char* kDst = (char*)Ks + w * 1024;
  // VT staging: wave w stages d-rows w*4 + jj*16 + (lane>>4), jj=0..3;
  // 16 groups/row; source group = (g&8)|((g&7)^(row&7)) (row&7 jj-invariant)
  int srowV = w * 4 + (lane >> 4);
  int gV = lane & 15;
  int sgcV = (gV & 8) | ((gV & 7) ^ (srowV & 7));
  const __bf16* vtSrc = VT + ((size_t)bh * 64 + srowV) * 2048 + sgcV * 8;
  char* vtDst = (char*)VTs + w * 1024;

#define ASTG(nb)                                                               \
  {                                                                            \
    _Pragma("unroll")                                                          \
    for (int j = 0; j < 4; j++) {                                              \
      gl_lds16(kSrc + j * 32768,  kDst + (nb) * 16384 + j * 4096);             \
      gl_lds16(vtSrc + j * 32768, vtDst + (nb) * 16384 + j * 4096);            \
    }                                                                          \
  }

  // prologue: stage tile 0 into buf 0
  ASTG(0)
  kSrc += 131072; vtSrc += 128;
  __syncthreads();

  for (int kt = 0; kt < 16; ++kt) {
    if (kt + 1 < 16) {           // stage next 128-kj tile into other buffer
      ASTG((kt + 1) & 1)
      kSrc += 131072; vtSrc += 128;
    }
    const __bf16* Ksb  = Ks  + (kt & 1) * 8192;
    const __bf16* VTsb = VTs + (kt & 1) * 8192;

#pragma unroll
    for (int kh = 0; kh < 2; kh++) {
      // ---- S^T = K.Q^T: kf reads shared by both q-groups ----
      f32x16 s_[2][2] = {};
      __builtin_amdgcn_s_setprio(1);
#pragma unroll
      for (int c = 0; c < 4; c++) {
        int g2 = c * 2 + hi;
        bf16x8 kf0 = *(const bf16x8*)&Ksb[(kh * 64 + ql) * 64 + ((g2 ^ (ql & 7)) * 8)];
        bf16x8 kf1 = *(const bf16x8*)&Ksb[(kh * 64 + 32 + ql) * 64 + ((g2 ^ (ql & 7)) * 8)];
#pragma unroll
        for (int g = 0; g < 2; g++) {
          s_[g][0] = __builtin_amdgcn_mfma_f32_32x32x16_bf16(kf0, qf[g][c], s_[g][0], 0, 0, 0);
          s_[g][1] = __builtin_amdgcn_mfma_f32_32x32x16_bf16(kf1, qf[g][c], s_[g][1], 0, 0, 0);
        }
      }
      __builtin_amdgcn_s_setprio(0);

      // ---- softmax per group (Q pre-scaled, no max-sub) -> P A-fragments ----
      unsigned int pa[2][2][2][4];
#pragma unroll
      for (int g = 0; g < 2; g++) {
#pragma unroll
        for (int h32 = 0; h32 < 2; h32++) {
          float p[16];
#pragma unroll
          for (int r = 0; r < 16; r++)
            p[r] = __builtin_amdgcn_exp2f(s_[g][h32][r]);
#pragma unroll
          for (int i = 0; i < 8; i++) {
            lsum2[g].x += p[2 * i];
            lsum2[g].y += p[2 * i + 1];
          }
          unsigned int cw[8];
#pragma unroll
          for (int i = 0; i < 8; i++) {
            unsigned int d_;
            asm("v_cvt_pk_bf16_f32 %0, %1, %2" : "=v"(d_) : "v"(p[2 * i]), "v"(p[2 * i + 1]));
            cw[i] = d_;
          }
          asm("v_permlane32_swap_b32 %0, %1" : "+v"(cw[2]), "+v"(cw[0]));
          asm("v_permlane32_swap_b32 %0, %1" : "+v"(cw[3]), "+v"(cw[1]));
          asm("v_permlane32_swap_b32 %0, %1" : "+v"(cw[6]), "+v"(cw[4]));
          asm("v_permlane32_swap_b32 %0, %1" : "+v"(cw[7]), "+v"(cw[5]));
          pa[g][h32][0][0] = cw[0]; pa[g][h32][0][1] = cw[1];
          pa[g][h32][0][2] = cw[2]; pa[g][h32][0][3] = cw[3];
          pa[g][h32][1][0] = cw[4]; pa[g][h32][1][1] = cw[5];
          pa[g][h32][1][2] = cw[6]; pa[g][h32][1][3] = cw[7];
        }
      }

      // ---- PV: vb reads shared by both q-groups ----
#pragma unroll
      for (int dh = 0; dh < 2; dh++) {
        int drow = dh * 32 + ql;
        int dsw = drow & 7;
        bf16x8 vb[4];
#pragma unroll
        for (int h32 = 0; h32 < 2; h32++)
#pragma unroll
          for (int kc = 0; kc < 2; kc++) {
            int g2 = h32 * 4 + kc * 2 + hi;  // kj group within kh-half
            vb[h32 * 2 + kc] = *(const bf16x8*)&VTsb[drow * 128 + ((kh * 8 + (g2 ^ dsw)) * 8)];
          }
        __builtin_amdgcn_s_setprio(1);
#pragma unroll
        for (int g = 0; g < 2; g++)
#pragma unroll
          for (int h32 = 0; h32 < 2; h32++)
#pragma unroll
            for (int kc = 0; kc < 2; kc++) {
              union { unsigned int u[4]; bf16x8 v; } A;
              A.u[0] = pa[g][h32][kc][0]; A.u[1] = pa[g][h32][kc][1];
              A.u[2] = pa[g][h32][kc][2]; A.u[3] = pa[g][h32][kc][3];
              oacc[g][dh] = __builtin_amdgcn_mfma_f32_32x32x16_bf16(A.v, vb[h32 * 2 + kc], oacc[g][dh], 0, 0, 0);
            }
        __builtin_amdgcn_s_setprio(0);
      }
    }
    __syncthreads();   // drains next-tile staging; protects buffer reuse
  }
#undef ASTG

  // ---- epilogue: divide by per-row l, write ----
#pragma unroll
  for (int g = 0; g < 2; g++) {
    float ls = lsum2[g].x + lsum2[g].y;
    float ltot = ls + __shfl_xor(ls, 32);
    if (hi == 0) lsm[w][g][ql] = ltot;
  }
  __syncthreads();
#pragma unroll
  for (int g = 0; g < 2; g++) {
    float rl[16];
#pragma unroll
    for (int r = 0; r < 16; r++)
      rl[r] = 1.0f / lsm[w][g][(r & 3) + 8 * (r >> 2) + 4 * hi];
    size_t obase = tokBase + qt * 256 + w * 64 + g * 32;
#pragma unroll
    for (int dh = 0; dh < 2; dh++)
#pragma unroll
      for (int r = 0; r < 16; r++) {
        int qrw = (r & 3) + 8 * (r >> 2) + 4 * hi;
        O[(obase + qrw) * 1024 + colBase + dh * 32 + ql] = (__bf16)(oacc[g][dh][r] * rl[r]);
      }
  }
}

// ---------------------------------------------------------------------------
extern "C" void kernel_launch(void* const* d_in, const int* in_sizes, int n_in,
                              void* d_out, int out_size, void* d_ws, size_t ws_size,
                              hipStream_t stream)
{
  const float* x         = (const float*)d_in[0];
  const float* rbb_ln_g  = (const float*)d_in[2];
  const float* rbb_ln_b  = (const float*)d_in[3];
  const float* rbb_W     = (const float*)d_in[4];
  const float* rbb_b     = (const float*)d_in[5];
  const float* rba_ln_g  = (const float*)d_in[6];
  const float* rba_ln_b  = (const float*)d_in[7];
  const float* rba_W     = (const float*)d_in[8];
  const float* rba_b     = (const float*)d_in[9];
  const float* attn_ln_g = (const float*)d_in[10];
  const float* attn_ln_b = (const float*)d_in[11];
  const float* Wq = (const float*)d_in[12];
  const float* bq = (const float*)d_in[13];
  const float* Wk = (const float*)d_in[14];
  const float* bk = (const float*)d_in[15];
  const float* Wv = (const float*)d_in[16];
  const float* bv = (const float*)d_in[17];
  const float* Wo = (const float*)d_in[18];
  const float* bo = (const float*)d_in[19];

  char* ws = (char*)d_ws;
  __bf16* X   = (__bf16*)(ws);                    // residual stream, bf16 16.8MB
  __bf16* Tb  = (__bf16*)(ws + 33554432);         // bf16 T (aliases Q region)
  __bf16* Qbf = (__bf16*)(ws + 33554432);
  __bf16* Kbf = (__bf16*)(ws + 33554432 + 16777216);
  __bf16* Abf = (__bf16*)(ws + 67108864);         // LN output
  __bf16* VT  = (__bf16*)(ws + 83886080);         // [4][16][64][2048] bf16
  __bf16* Cbf = (__bf16*)(ws + 100663296);        // attn output
  __bf16* Wbf = (__bf16*)(ws + 117440512);        // 24 weight matrices (48MB)
  auto WT = [&](int m) { return Wbf + (size_t)m * 1048576; };

  float* outF = (float*)d_out;
  dim3 blk(256);

  wt_conv<<<24 * 1024, blk, 0, stream>>>(rbb_W, Wq, Wk, Wv, Wo, rba_W, Wbf);

  // rbb resnet (block 0 residual = f32 input x; block 1 residual = bf16 X)
  ln_relu<0><<<8192, blk, 0, stream>>>(x, rbb_ln_g + 0 * 1024, rbb_ln_b + 0 * 1024, Abf);
  gemm_bt<0, 1><<<512, blk, 0, stream>>>(Abf, WT(0), rbb_b + 0 * 1024, nullptr, nullptr, Tb);
  ln_relu<1><<<8192, blk, 0, stream>>>(Tb, rbb_ln_g + 1 * 1024, rbb_ln_b + 1 * 1024, Abf);
  gemm_bt<1, 1><<<512, blk, 0, stream>>>(Abf, WT(1), rbb_b + 1 * 1024, x, nullptr, X);

  ln_relu<1><<<8192, blk, 0, stream>>>(X, rbb_ln_g + 2 * 1024, rbb_ln_b + 2 * 1024, Abf);
  gemm_bt<0, 1><<<512, blk, 0, stream>>>(Abf, WT(2), rbb_b + 2 * 1024, nullptr, nullptr, Tb);
  ln_relu<1><<<8192, blk, 0, stream>>>(Tb, rbb_ln_g + 3 * 1024, rbb_ln_b + 3 * 1024, Abf);
  gemm_bt<2, 1><<<512, blk, 0, stream>>>(Abf, WT(3), rbb_b + 3 * 1024, X, nullptr, X);

  // attention layers (fused QKV projection)
  for (int l = 0; l < 4; l++) {
    ln_relu<1><<<8192, blk, 0, stream>>>(X, attn_ln_g + l * 1024, attn_ln_b + l * 1024, Abf);
    gemm_qkv<<<1536, blk, 0, stream>>>(Abf, WT(4 + 3 * l),
                                       bq + l * 1024, bk + l * 1024, bv + l * 1024,
                                       Qbf, Kbf, VT);
    attn_fwd<<<512, blk, 0, stream>>>(Qbf, Kbf, VT, Cbf);
    gemm_bt<2, 1><<<512, blk, 0, stream>>>(Cbf, WT(16 + l), bo + l * 1024, X, nullptr, X);
  }

  // rba resnet (last GEMM writes f32 d_out directly)
  for (int i = 0; i < 2; i++) {
    ln_relu<1><<<8192, blk, 0, stream>>>(X, rba_ln_g + (i * 2 + 0) * 1024, rba_ln_b + (i * 2 + 0) * 1024, Abf);
    gemm_bt<0, 1><<<512, blk, 0, stream>>>(Abf, WT(20 + i * 2 + 0), rba_b + (i * 2 + 0) * 1024, nullptr, nullptr, Tb);
    ln_relu<1><<<8192, blk, 0, stream>>>(Tb, rba_ln_g + (i * 2 + 1) * 1024, rba_ln_b + (i * 2 + 1) * 1024, Abf);
    if (i == 0)
      gemm_bt<2, 1><<<512, blk, 0, stream>>>(Abf, WT(21), rba_b + 1 * 1024, X, nullptr, X);
    else
      gemm_bt<2, 0><<<512, blk, 0, stream>>>(Abf, WT(23), rba_b + 3 * 1024, X, outF, nullptr);
  }
}